// Round 1
// 456.192 us; speedup vs baseline: 1.7932x; 1.7932x over previous
//
#include <hip/hip_runtime.h>
#include <math.h>
#include <stdint.h>

#define NT 32768
#define DM 1024
#define NC 4096
#define CD 256

#define X_F4 (DM/4)
#define W_F4 (CD/4)
#define Z_F4 (CD/4)
#define C_F4 (CD/4)

typedef __attribute__((ext_vector_type(8))) short bf16x8;
typedef __attribute__((ext_vector_type(4))) float floatx4;

__device__ __forceinline__ unsigned short f2bf(float f) {
    union { float f; uint32_t u; } v; v.f = f;
    uint32_t u = v.u;
    u += 0x7FFFu + ((u >> 16) & 1u);   // RN-even
    return (unsigned short)(u >> 16);
}

// split x into hi (truncated bf16) + lo (RNE bf16 of exact f32 residual)
__device__ __forceinline__ void split8(const float4 f0, const float4 f1,
                                       bf16x8& h, bf16x8& l) {
    float f[8] = {f0.x, f0.y, f0.z, f0.w, f1.x, f1.y, f1.z, f1.w};
    #pragma unroll
    for (int j = 0; j < 8; ++j) {
        union { float f; uint32_t u; } v; v.f = f[j];
        h[j] = (short)(v.u >> 16);
        union { uint32_t u; float f; } t; t.u = v.u & 0xFFFF0000u;
        l[j] = (short)f2bf(f[j] - t.f);
    }
}

// ---------------------------------------------------------------------------
// K0: per-code prep: hn2[code] = 0.5*||c||^2 - 2  (key shift makes s' in
// [0.5,2.5] > 0 so u32 bit-compare == float compare), plus bf16 codebook.
// ---------------------------------------------------------------------------
__global__ __launch_bounds__(256) void k0_prep(const float4* __restrict__ cb,
                                               float* __restrict__ hn2,
                                               ushort* __restrict__ cbb) {
    int wid = threadIdx.x >> 6, lane = threadIdx.x & 63;
    int code = blockIdx.x * 4 + wid;
    float4 c = cb[(size_t)code * C_F4 + lane];
    ushort4 h;
    h.x = f2bf(c.x); h.y = f2bf(c.y); h.z = f2bf(c.z); h.w = f2bf(c.w);
    ((ushort4*)cbb)[(size_t)code * 64 + lane] = h;
    float ss = c.x*c.x + c.y*c.y + c.z*c.z + c.w*c.w;
    #pragma unroll
    for (int m = 32; m >= 1; m >>= 1) ss += __shfl_xor(ss, m, 64);
    if (lane == 0) hn2[code] = 0.5f * ss - 2.0f;
}

// ---------------------------------------------------------------------------
// K0b: W [1024][256] f32 -> transposed split-bf16 WT_hi/WT_lo [256][1024].
// Each block handles a 16-row k-slab; LDS transpose; coalesced-ish writes.
// ---------------------------------------------------------------------------
__global__ __launch_bounds__(256) void k0b_wsplit(const float4* __restrict__ W,
                                                  ushort* __restrict__ WTh,
                                                  ushort* __restrict__ WTl) {
    __shared__ float lds[16][260];
    int slab = blockIdx.x;              // 64 slabs of 16 k-rows
    int tid = threadIdx.x;
    #pragma unroll
    for (int jj = 0; jj < 4; ++jj) {
        int v = jj * 256 + tid;         // 0..1023
        int row = v >> 6, f4 = v & 63;
        float4 d = W[(size_t)(slab * 16 + row) * W_F4 + f4];
        *(float4*)&lds[row][f4 * 4] = d;
    }
    __syncthreads();
    int c = tid;                        // column (n) 0..255
    #pragma unroll
    for (int kb = 0; kb < 2; ++kb) {
        bf16x8 h, l;
        #pragma unroll
        for (int j = 0; j < 8; ++j) {
            float x = lds[kb * 8 + j][c];
            union { float f; uint32_t u; } v; v.f = x;
            h[j] = (short)(v.u >> 16);
            union { uint32_t u; float f; } t; t.u = v.u & 0xFFFF0000u;
            l[j] = (short)f2bf(x - t.f);
        }
        size_t off = (size_t)c * 1024 + slab * 16 + kb * 8;
        *(bf16x8*)(WTh + off) = h;
        *(bf16x8*)(WTl + off) = l;
    }
}

// ---------------------------------------------------------------------------
// K1: z_pre = x @ W_down via split-bf16 MFMA (Ootomo 3-term: hh + hl + lh).
// 512 blocks (256 mb x 2 nb), 128x128 tile, 4 waves 2x2, 64x64 per wave.
// BK=64, 16 kt iters, single LDS buffer + register prefetch (K2 pattern).
// X converted f32->hi/lo bf16 in-register at staging; W pre-split by k0b.
// Operands swapped in MFMA so acc maps to float4 stores of Zp.
// ---------------------------------------------------------------------------
__global__ __launch_bounds__(256, 2) void k1_gemm1(const float4* __restrict__ X,
                                                   const ushort* __restrict__ WTh,
                                                   const ushort* __restrict__ WTl,
                                                   float4* __restrict__ Zp) {
    __shared__ __align__(16) char lds[65536];
    char* Ah = lds;              // 128 rows x 64 bf16 (swizzled chunks)
    char* Al = lds + 16384;
    char* Bh = lds + 32768;      // 128 cols(n) x 64 bf16
    char* Bl = lds + 49152;

    int tid  = threadIdx.x;
    int w    = tid >> 6, lane = tid & 63;
    int wm   = w >> 1, wn = w & 1;
    int c    = lane & 15, q = lane >> 4;
    int mb   = blockIdx.x >> 1, nb = blockIdx.x & 1;
    int m0   = mb * 128;
    int n0   = nb * 128;

    auto issue_loads = [&](int kt, float4* ga, bf16x8* gbh, bf16x8* gbl) {
        #pragma unroll
        for (int jj = 0; jj < 4; ++jj) {
            int v = jj * 256 + tid;           // 0..1023
            int row = v >> 3, ch = v & 7;
            const float4* p = X + (size_t)(m0 + row) * X_F4 + kt * 16 + ch * 2;
            ga[jj * 2]     = p[0];
            ga[jj * 2 + 1] = p[1];
        }
        #pragma unroll
        for (int jj = 0; jj < 4; ++jj) {
            int v = jj * 256 + tid;
            int col = v >> 3, ch = v & 7;
            size_t off = (size_t)(n0 + col) * 1024 + kt * 64 + ch * 8;
            gbh[jj] = *(const bf16x8*)(WTh + off);
            gbl[jj] = *(const bf16x8*)(WTl + off);
        }
    };
    auto write_lds = [&](const float4* ga, const bf16x8* gbh, const bf16x8* gbl) {
        #pragma unroll
        for (int jj = 0; jj < 4; ++jj) {
            int v = jj * 256 + tid;
            int row = v >> 3, ch = v & 7;
            bf16x8 h, l;
            split8(ga[jj * 2], ga[jj * 2 + 1], h, l);
            int off = row * 128 + ((ch ^ (row & 7)) << 4);
            *(bf16x8*)(Ah + off) = h;
            *(bf16x8*)(Al + off) = l;
        }
        #pragma unroll
        for (int jj = 0; jj < 4; ++jj) {
            int v = jj * 256 + tid;
            int col = v >> 3, ch = v & 7;
            int off = col * 128 + ((ch ^ (col & 7)) << 4);
            *(bf16x8*)(Bh + off) = gbh[jj];
            *(bf16x8*)(Bl + off) = gbl[jj];
        }
    };

    floatx4 acc[4][4];
    #pragma unroll
    for (int i = 0; i < 4; ++i)
        #pragma unroll
        for (int j = 0; j < 4; ++j) acc[i][j] = (floatx4){0.f, 0.f, 0.f, 0.f};

    float4 ga[8]; bf16x8 gbh[4], gbl[4];
    issue_loads(0, ga, gbh, gbl);
    write_lds(ga, gbh, gbl);

    for (int kt = 0; kt < 16; ++kt) {
        __syncthreads();
        if (kt < 15) issue_loads(kt + 1, ga, gbh, gbl);

        #pragma unroll
        for (int ks = 0; ks < 2; ++ks) {
            bf16x8 xh[4], xl[4], wh[4], wl[4];
            #pragma unroll
            for (int i = 0; i < 4; ++i) {
                int xrow = wm * 64 + i * 16 + c;
                int xoff = xrow * 128 + (((ks * 4 + q) ^ (xrow & 7)) << 4);
                xh[i] = *(const bf16x8*)(Ah + xoff);
                xl[i] = *(const bf16x8*)(Al + xoff);
                int wrow = wn * 64 + i * 16 + c;
                int woff = wrow * 128 + (((ks * 4 + q) ^ (wrow & 7)) << 4);
                wh[i] = *(const bf16x8*)(Bh + woff);
                wl[i] = *(const bf16x8*)(Bl + woff);
            }
            #pragma unroll
            for (int xi = 0; xi < 4; ++xi)
                #pragma unroll
                for (int ni = 0; ni < 4; ++ni) {
                    acc[xi][ni] = __builtin_amdgcn_mfma_f32_16x16x32_bf16(wh[ni], xh[xi], acc[xi][ni], 0, 0, 0);
                    acc[xi][ni] = __builtin_amdgcn_mfma_f32_16x16x32_bf16(wh[ni], xl[xi], acc[xi][ni], 0, 0, 0);
                    acc[xi][ni] = __builtin_amdgcn_mfma_f32_16x16x32_bf16(wl[ni], xh[xi], acc[xi][ni], 0, 0, 0);
                }
        }

        __syncthreads();
        if (kt < 15) write_lds(ga, gbh, gbl);
    }

    // C/D layout: col = lane&15 -> token, row = (lane>>4)*4 + reg -> n.
    // Each acc frag = 4 consecutive n at one token -> one float4 store.
    #pragma unroll
    for (int xi = 0; xi < 4; ++xi) {
        int tok = m0 + wm * 64 + xi * 16 + c;
        #pragma unroll
        for (int ni = 0; ni < 4; ++ni) {
            int nf4 = nb * 32 + wn * 16 + ni * 4 + q;
            float4 o;
            o.x = acc[xi][ni][0]; o.y = acc[xi][ni][1];
            o.z = acc[xi][ni][2]; o.w = acc[xi][ni][3];
            Zp[(size_t)tok * Z_F4 + nf4] = o;
        }
    }
}

// ---------------------------------------------------------------------------
// K1b: z = (z_pre + b) / (||z_pre + b|| + 1e-6) (unchanged)
// ---------------------------------------------------------------------------
__global__ __launch_bounds__(256) void k1b_norm(float4* __restrict__ Z,
                                                const float4* __restrict__ bias) {
    int wid = threadIdx.x >> 6, lane = threadIdx.x & 63;
    int t = blockIdx.x * 4 + wid;
    float4 b = bias[lane];
    float4 z = Z[(size_t)t * Z_F4 + lane];
    z.x += b.x; z.y += b.y; z.z += b.z; z.w += b.w;
    double ss = (double)z.x*z.x + (double)z.y*z.y + (double)z.z*z.z + (double)z.w*z.w;
    #pragma unroll
    for (int m = 32; m >= 1; m >>= 1) ss += __shfl_xor(ss, m, 64);
    float inv = 1.0f / ((float)sqrt(ss) + 1e-6f);
    z.x *= inv; z.y *= inv; z.z *= inv; z.w *= inv;
    Z[(size_t)t * Z_F4 + lane] = z;
}

// ---------------------------------------------------------------------------
// K2: bf16 MFMA candidate scoring.
// Block = 4 waves, 64 tokens. Each wave: same 64 tokens (A in 128 VGPRs,
// loop-invariant, converted f32->bf16 in-register), code quarter w of each
// 64-code tile. 64 tiles. Per tile per wave: 8 ds_read_b128 (XOR-swizzled
// LDS) : 32 MFMA. Scores packed into sortable u32 keys (15 high float bits +
// 6-bit tile id); per-lane running top-2 via 3x max/min; end: LDS merge ->
// global top-4 per token -> cands (int4). Code 0 replaced by code 1 at
// staging (excluded later in K3).
// ---------------------------------------------------------------------------
__global__ __launch_bounds__(256, 2) void k2_mfma(const float* __restrict__ Z,
                                                  const ushort* __restrict__ Cbb,
                                                  const float* __restrict__ hn2g,
                                                  int4* __restrict__ cands) {
    __shared__ __align__(16) char lds[32768 + 256];  // B tile + hn2; merge reuses B

    int tid  = threadIdx.x;
    int w    = tid >> 6;         // wave id = code quarter
    int lane = tid & 63;
    int c    = lane & 15, q = lane >> 4;
    int t0   = blockIdx.x * 64;

    // ---- A fragments: 4 mi x 8 ks, f32 -> bf16 in-register
    bf16x8 A[4][8];
    #pragma unroll
    for (int mi = 0; mi < 4; ++mi) {
        #pragma unroll
        for (int ks = 0; ks < 8; ++ks) {
            const float* zp = Z + (size_t)(t0 + mi * 16 + c) * CD + ks * 32 + q * 8;
            float4 f0 = *(const float4*)zp;
            float4 f1 = *(const float4*)(zp + 4);
            bf16x8 a;
            a[0] = (short)f2bf(f0.x); a[1] = (short)f2bf(f0.y);
            a[2] = (short)f2bf(f0.z); a[3] = (short)f2bf(f0.w);
            a[4] = (short)f2bf(f1.x); a[5] = (short)f2bf(f1.y);
            a[6] = (short)f2bf(f1.z); a[7] = (short)f2bf(f1.w);
            A[mi][ks] = a;
        }
    }

    // ---- per-lane B read addresses (invariant across tiles)
    int baddr[8];
    #pragma unroll
    for (int ks = 0; ks < 8; ++ks)
        baddr[ks] = (w * 16 + c) * 512 + ((((ks * 4 + q) ^ c)) << 4);
    int hnaddr = 32768 + (w * 16 + c) * 4;

    auto issue_loads = [&](int ct, bf16x8* g, float& hnr) {
        #pragma unroll
        for (int jj = 0; jj < 8; ++jj) {
            int v = jj * 256 + tid;
            int row = v >> 5, ch = v & 31;
            int grow = ct * 64 + row; if (grow < 1) grow = 1;   // exclude code 0
            g[jj] = *(const bf16x8*)(Cbb + (size_t)grow * CD + ch * 8);
        }
        if (tid < 64) {
            int gc = ct * 64 + tid; if (gc < 1) gc = 1;
            hnr = hn2g[gc];
        }
    };
    auto write_lds = [&](const bf16x8* g, float hnr) {
        #pragma unroll
        for (int jj = 0; jj < 8; ++jj) {
            int v = jj * 256 + tid;
            int row = v >> 5, ch = v & 31;
            *(bf16x8*)(lds + row * 512 + ((ch ^ (row & 15)) << 4)) = g[jj];
        }
        if (tid < 64) *(float*)(lds + 32768 + tid * 4) = hnr;
    };

    uint32_t K1[16], K2[16];
    #pragma unroll
    for (int i = 0; i < 16; ++i) { K1[i] = 0u; K2[i] = 0u; }

    bf16x8 g[8]; float hnr = 0.0f;
    issue_loads(0, g, hnr);
    write_lds(g, hnr);

    for (int ct = 0; ct < 64; ++ct) {
        __syncthreads();
        bf16x8 g2[8]; float hnr2 = 0.0f;
        if (ct < 63) issue_loads(ct + 1, g2, hnr2);

        floatx4 C[4];
        #pragma unroll
        for (int mi = 0; mi < 4; ++mi) C[mi] = (floatx4){0.f, 0.f, 0.f, 0.f};

        #pragma unroll
        for (int ks = 0; ks < 8; ++ks) {
            bf16x8 Bf = *(const bf16x8*)(lds + baddr[ks]);
            #pragma unroll
            for (int mi = 0; mi < 4; ++mi)
                C[mi] = __builtin_amdgcn_mfma_f32_16x16x32_bf16(A[mi][ks], Bf, C[mi], 0, 0, 0);
        }

        float hv = *(const float*)(lds + hnaddr);
        #pragma unroll
        for (int mi = 0; mi < 4; ++mi) {
            #pragma unroll
            for (int r = 0; r < 4; ++r) {
                float sp = C[mi][r] - hv;              // = z.c + 1.5, in [0.5,2.5]
                union { float f; uint32_t u; } uv; uv.f = sp;
                uint32_t key = (uv.u & 0xFFFFFFC0u) | (uint32_t)ct;
                int i = mi * 4 + r;
                uint32_t lo = key < K1[i] ? key : K1[i];
                K1[i] = key > K1[i] ? key : K1[i];
                K2[i] = lo > K2[i] ? lo : K2[i];
            }
        }

        __syncthreads();
        if (ct < 63) write_lds(g2, hnr2);
    }

    // ---- merge: per token, 4 waves x 16 lanes x top-2 = 128 keys -> top-4
    __syncthreads();
    uint32_t* M = (uint32_t*)lds;   // [tok][w][c][2]
    #pragma unroll
    for (int mi = 0; mi < 4; ++mi) {
        #pragma unroll
        for (int r = 0; r < 4; ++r) {
            int tok = mi * 16 + q * 4 + r;
            int base = ((tok * 4 + w) * 16 + c) * 2;
            M[base]     = K1[mi * 4 + r];
            M[base + 1] = K2[mi * 4 + r];
        }
    }
    __syncthreads();
    if (tid < 64) {
        int tok = tid;
        uint32_t bk0 = 0, bk1 = 0, bk2 = 0, bk3 = 0;
        int      bp0 = 0, bp1 = 0, bp2 = 0, bp3 = 0;
        for (int e = 0; e < 128; ++e) {
            uint32_t key = M[tok * 128 + e];
            int pos = e >> 1;   // = w*16 + c
            if (key > bk0) {
                bk3 = bk2; bp3 = bp2; bk2 = bk1; bp2 = bp1;
                bk1 = bk0; bp1 = bp0; bk0 = key; bp0 = pos;
            } else if (key > bk1) {
                bk3 = bk2; bp3 = bp2; bk2 = bk1; bp2 = bp1; bk1 = key; bp1 = pos;
            } else if (key > bk2) {
                bk3 = bk2; bp3 = bp2; bk2 = key; bp2 = pos;
            } else if (key > bk3) {
                bk3 = key; bp3 = pos;
            }
        }
        int4 out;
        out.x = (int)(bk0 & 63u) * 64 + bp0;
        out.y = (int)(bk1 & 63u) * 64 + bp1;
        out.z = (int)(bk2 & 63u) * 64 + bp2;
        out.w = (int)(bk3 & 63u) * 64 + bp3;
        cands[t0 + tok] = out;
    }
}

// ---------------------------------------------------------------------------
// K3: f64 re-rank of 4 candidates (code 0 invalid; ties -> lowest index),
// write index (as float) + gather hard code. One wave per token.
// ---------------------------------------------------------------------------
__global__ __launch_bounds__(256) void k3_refine(const float4* __restrict__ Z,
                                                 const float4* __restrict__ Cb,
                                                 const int4* __restrict__ cands,
                                                 float* __restrict__ idxOut,
                                                 float4* __restrict__ hardOut) {
    int wid = threadIdx.x >> 6, lane = threadIdx.x & 63;
    int t = blockIdx.x * 4 + wid;
    int4 cd = cands[t];
    int cc[4] = {cd.x, cd.y, cd.z, cd.w};
    float4 z = Z[(size_t)t * Z_F4 + lane];
    double best = -1.0e300;
    int bi = NC;   // sentinel
    #pragma unroll
    for (int e = 0; e < 4; ++e) {
        int idx = cc[e];
        float4 cf = Cb[(size_t)idx * C_F4 + lane];
        double dot = (double)z.x*cf.x + (double)z.y*cf.y + (double)z.z*cf.z + (double)z.w*cf.w;
        double nrm = (double)cf.x*cf.x + (double)cf.y*cf.y + (double)cf.z*cf.z + (double)cf.w*cf.w;
        #pragma unroll
        for (int m = 32; m >= 1; m >>= 1) {
            dot += __shfl_xor(dot, m, 64);
            nrm += __shfl_xor(nrm, m, 64);
        }
        double s = dot - 0.5 * nrm;
        if (idx >= 1 && (s > best || (s == best && idx < bi))) { best = s; bi = idx; }
    }
    if (lane == 0) idxOut[t] = (float)bi;
    hardOut[(size_t)t * C_F4 + lane] = Cb[(size_t)bi * C_F4 + lane];
}

// ---------------------------------------------------------------------------
extern "C" void kernel_launch(void* const* d_in, const int* in_sizes, int n_in,
                              void* d_out, int out_size, void* d_ws, size_t ws_size,
                              hipStream_t stream) {
    const float* x  = (const float*)d_in[0];   // 32768 x 1024
    const float* cb = (const float*)d_in[1];   // 4096 x 256
    const float* w  = (const float*)d_in[2];   // 1024 x 256
    const float* bd = (const float*)d_in[3];   // 256

    float* zOut    = (float*)d_out;                    // 32768 x 256
    float* idxOut  = zOut + (size_t)NT * CD;           // 32768 (as float values)
    float* hardOut = idxOut + NT;                      // 32768 x 256

    float*  hn2   = (float*)d_ws;                            // 16 KB
    int4*   cands = (int4*)((char*)d_ws + 16384);            // 512 KB
    ushort* cbb   = (ushort*)((char*)d_ws + 16384 + 524288); // 2 MB bf16 codebook
    ushort* wth   = (ushort*)((char*)d_ws + 2637824);        // 512 KB bf16 W^T hi
    ushort* wtl   = (ushort*)((char*)d_ws + 3162112);        // 512 KB bf16 W^T lo

    k0_prep<<<NC / 4, 256, 0, stream>>>((const float4*)cb, hn2, cbb);
    k0b_wsplit<<<DM / 16, 256, 0, stream>>>((const float4*)w, wth, wtl);
    k1_gemm1<<<(NT / 128) * 2, 256, 0, stream>>>((const float4*)x, wth, wtl,
                                                 (float4*)zOut);
    k1b_norm<<<NT / 4, 256, 0, stream>>>((float4*)zOut, (const float4*)bd);
    k2_mfma<<<NT / 64, 256, 0, stream>>>(zOut, cbb, hn2, cands);
    k3_refine<<<NT / 4, 256, 0, stream>>>((const float4*)zOut, (const float4*)cb,
                                          cands, idxOut, (float4*)hardOut);
}

// Round 3
// 443.307 us; speedup vs baseline: 1.8454x; 1.0291x over previous
//
#include <hip/hip_runtime.h>
#include <math.h>
#include <stdint.h>

#define NT 32768
#define DM 1024
#define NC 4096
#define CD 256

#define X_F4 (DM/4)
#define W_F4 (CD/4)
#define Z_F4 (CD/4)
#define C_F4 (CD/4)

typedef __attribute__((ext_vector_type(8))) short bf16x8;
typedef __attribute__((ext_vector_type(4))) float floatx4;

__device__ __forceinline__ unsigned short f2bf(float f) {
    union { float f; uint32_t u; } v; v.f = f;
    uint32_t u = v.u;
    u += 0x7FFFu + ((u >> 16) & 1u);   // RN-even
    return (unsigned short)(u >> 16);
}

// split x into hi (truncated bf16) + lo (RNE bf16 of exact f32 residual)
__device__ __forceinline__ void split8(const float4 f0, const float4 f1,
                                       bf16x8& h, bf16x8& l) {
    float f[8] = {f0.x, f0.y, f0.z, f0.w, f1.x, f1.y, f1.z, f1.w};
    #pragma unroll
    for (int j = 0; j < 8; ++j) {
        union { float f; uint32_t u; } v; v.f = f[j];
        h[j] = (short)(v.u >> 16);
        union { uint32_t u; float f; } t; t.u = v.u & 0xFFFF0000u;
        l[j] = (short)f2bf(f[j] - t.f);
    }
}

// ---------------------------------------------------------------------------
// K0: per-code prep: hn2[code] = 0.5*||c||^2 - 2  (key shift makes s' in
// [0.5,2.5] > 0 so u32 bit-compare == float compare), plus bf16 codebook.
// ---------------------------------------------------------------------------
__global__ __launch_bounds__(256) void k0_prep(const float4* __restrict__ cb,
                                               float* __restrict__ hn2,
                                               ushort* __restrict__ cbb) {
    int wid = threadIdx.x >> 6, lane = threadIdx.x & 63;
    int code = blockIdx.x * 4 + wid;
    float4 c = cb[(size_t)code * C_F4 + lane];
    ushort4 h;
    h.x = f2bf(c.x); h.y = f2bf(c.y); h.z = f2bf(c.z); h.w = f2bf(c.w);
    ((ushort4*)cbb)[(size_t)code * 64 + lane] = h;
    float ss = c.x*c.x + c.y*c.y + c.z*c.z + c.w*c.w;
    #pragma unroll
    for (int m = 32; m >= 1; m >>= 1) ss += __shfl_xor(ss, m, 64);
    if (lane == 0) hn2[code] = 0.5f * ss - 2.0f;
}

// ---------------------------------------------------------------------------
// K0b: W [1024][256] f32 -> transposed split-bf16 WT_hi/WT_lo [256][1024].
// ---------------------------------------------------------------------------
__global__ __launch_bounds__(256) void k0b_wsplit(const float4* __restrict__ W,
                                                  ushort* __restrict__ WTh,
                                                  ushort* __restrict__ WTl) {
    __shared__ float lds[16][260];
    int slab = blockIdx.x;              // 64 slabs of 16 k-rows
    int tid = threadIdx.x;
    #pragma unroll
    for (int jj = 0; jj < 4; ++jj) {
        int v = jj * 256 + tid;         // 0..1023
        int row = v >> 6, f4 = v & 63;
        float4 d = W[(size_t)(slab * 16 + row) * W_F4 + f4];
        *(float4*)&lds[row][f4 * 4] = d;
    }
    __syncthreads();
    int c = tid;                        // column (n) 0..255
    #pragma unroll
    for (int kb = 0; kb < 2; ++kb) {
        bf16x8 h, l;
        #pragma unroll
        for (int j = 0; j < 8; ++j) {
            float x = lds[kb * 8 + j][c];
            union { float f; uint32_t u; } v; v.f = x;
            h[j] = (short)(v.u >> 16);
            union { uint32_t u; float f; } t; t.u = v.u & 0xFFFF0000u;
            l[j] = (short)f2bf(x - t.f);
        }
        size_t off = (size_t)c * 1024 + slab * 16 + kb * 8;
        *(bf16x8*)(WTh + off) = h;
        *(bf16x8*)(WTl + off) = l;
    }
}

// ---------------------------------------------------------------------------
// K1: z_pre = x @ W_down via split-bf16 MFMA (Ootomo 3-term: hh + hl + lh).
// ---------------------------------------------------------------------------
__global__ __launch_bounds__(256, 2) void k1_gemm1(const float4* __restrict__ X,
                                                   const ushort* __restrict__ WTh,
                                                   const ushort* __restrict__ WTl,
                                                   float4* __restrict__ Zp) {
    __shared__ __align__(16) char lds[65536];
    char* Ah = lds;              // 128 rows x 64 bf16 (swizzled chunks)
    char* Al = lds + 16384;
    char* Bh = lds + 32768;      // 128 cols(n) x 64 bf16
    char* Bl = lds + 49152;

    int tid  = threadIdx.x;
    int w    = tid >> 6, lane = tid & 63;
    int wm   = w >> 1, wn = w & 1;
    int c    = lane & 15, q = lane >> 4;
    int mb   = blockIdx.x >> 1, nb = blockIdx.x & 1;
    int m0   = mb * 128;
    int n0   = nb * 128;

    auto issue_loads = [&](int kt, float4* ga, bf16x8* gbh, bf16x8* gbl) {
        #pragma unroll
        for (int jj = 0; jj < 4; ++jj) {
            int v = jj * 256 + tid;           // 0..1023
            int row = v >> 3, ch = v & 7;
            const float4* p = X + (size_t)(m0 + row) * X_F4 + kt * 16 + ch * 2;
            ga[jj * 2]     = p[0];
            ga[jj * 2 + 1] = p[1];
        }
        #pragma unroll
        for (int jj = 0; jj < 4; ++jj) {
            int v = jj * 256 + tid;
            int col = v >> 3, ch = v & 7;
            size_t off = (size_t)(n0 + col) * 1024 + kt * 64 + ch * 8;
            gbh[jj] = *(const bf16x8*)(WTh + off);
            gbl[jj] = *(const bf16x8*)(WTl + off);
        }
    };
    auto write_lds = [&](const float4* ga, const bf16x8* gbh, const bf16x8* gbl) {
        #pragma unroll
        for (int jj = 0; jj < 4; ++jj) {
            int v = jj * 256 + tid;
            int row = v >> 3, ch = v & 7;
            bf16x8 h, l;
            split8(ga[jj * 2], ga[jj * 2 + 1], h, l);
            int off = row * 128 + ((ch ^ (row & 7)) << 4);
            *(bf16x8*)(Ah + off) = h;
            *(bf16x8*)(Al + off) = l;
        }
        #pragma unroll
        for (int jj = 0; jj < 4; ++jj) {
            int v = jj * 256 + tid;
            int col = v >> 3, ch = v & 7;
            int off = col * 128 + ((ch ^ (col & 7)) << 4);
            *(bf16x8*)(Bh + off) = gbh[jj];
            *(bf16x8*)(Bl + off) = gbl[jj];
        }
    };

    floatx4 acc[4][4];
    #pragma unroll
    for (int i = 0; i < 4; ++i)
        #pragma unroll
        for (int j = 0; j < 4; ++j) acc[i][j] = (floatx4){0.f, 0.f, 0.f, 0.f};

    float4 ga[8]; bf16x8 gbh[4], gbl[4];
    issue_loads(0, ga, gbh, gbl);
    write_lds(ga, gbh, gbl);

    for (int kt = 0; kt < 16; ++kt) {
        __syncthreads();
        if (kt < 15) issue_loads(kt + 1, ga, gbh, gbl);

        #pragma unroll
        for (int ks = 0; ks < 2; ++ks) {
            bf16x8 xh[4], xl[4], wh[4], wl[4];
            #pragma unroll
            for (int i = 0; i < 4; ++i) {
                int xrow = wm * 64 + i * 16 + c;
                int xoff = xrow * 128 + (((ks * 4 + q) ^ (xrow & 7)) << 4);
                xh[i] = *(const bf16x8*)(Ah + xoff);
                xl[i] = *(const bf16x8*)(Al + xoff);
                int wrow = wn * 64 + i * 16 + c;
                int woff = wrow * 128 + (((ks * 4 + q) ^ (wrow & 7)) << 4);
                wh[i] = *(const bf16x8*)(Bh + woff);
                wl[i] = *(const bf16x8*)(Bl + woff);
            }
            #pragma unroll
            for (int xi = 0; xi < 4; ++xi)
                #pragma unroll
                for (int ni = 0; ni < 4; ++ni) {
                    acc[xi][ni] = __builtin_amdgcn_mfma_f32_16x16x32_bf16(wh[ni], xh[xi], acc[xi][ni], 0, 0, 0);
                    acc[xi][ni] = __builtin_amdgcn_mfma_f32_16x16x32_bf16(wh[ni], xl[xi], acc[xi][ni], 0, 0, 0);
                    acc[xi][ni] = __builtin_amdgcn_mfma_f32_16x16x32_bf16(wl[ni], xh[xi], acc[xi][ni], 0, 0, 0);
                }
        }

        __syncthreads();
        if (kt < 15) write_lds(ga, gbh, gbl);
    }

    #pragma unroll
    for (int xi = 0; xi < 4; ++xi) {
        int tok = m0 + wm * 64 + xi * 16 + c;
        #pragma unroll
        for (int ni = 0; ni < 4; ++ni) {
            int nf4 = nb * 32 + wn * 16 + ni * 4 + q;
            float4 o;
            o.x = acc[xi][ni][0]; o.y = acc[xi][ni][1];
            o.z = acc[xi][ni][2]; o.w = acc[xi][ni][3];
            Zp[(size_t)tok * Z_F4 + nf4] = o;
        }
    }
}

// ---------------------------------------------------------------------------
// K1b: z = (z_pre + b) / (||z_pre + b|| + 1e-6) (unchanged)
// ---------------------------------------------------------------------------
__global__ __launch_bounds__(256) void k1b_norm(float4* __restrict__ Z,
                                                const float4* __restrict__ bias) {
    int wid = threadIdx.x >> 6, lane = threadIdx.x & 63;
    int t = blockIdx.x * 4 + wid;
    float4 b = bias[lane];
    float4 z = Z[(size_t)t * Z_F4 + lane];
    z.x += b.x; z.y += b.y; z.z += b.z; z.w += b.w;
    double ss = (double)z.x*z.x + (double)z.y*z.y + (double)z.z*z.z + (double)z.w*z.w;
    #pragma unroll
    for (int m = 32; m >= 1; m >>= 1) ss += __shfl_xor(ss, m, 64);
    float inv = 1.0f / ((float)sqrt(ss) + 1e-6f);
    z.x *= inv; z.y *= inv; z.z *= inv; z.w *= inv;
    Z[(size_t)t * Z_F4 + lane] = z;
}

// ---------------------------------------------------------------------------
// K2 v2: barrier-free bf16 MFMA candidate scoring.
// Block = 4 waves, 64 tokens, 512 blocks. Each wave owns a 16-code quarter
// of every 64-code tile and reads its B fragments DIRECTLY from global
// (L2-resident 2MB codebook) in MFMA fragment layout — no LDS staging, no
// main-loop __syncthreads. Register double-buffer (B0/B1, unroll-by-2).
// Accumulator initialized to -hn2 (folds the score shift, saves the sub).
// Scores packed into sortable u32 keys (17 float bits + 6-bit tile id);
// per-lane running top-2; merge parallelized over all 256 threads with
// padded LDS strides (conflict-free vs the old 62-way serial scan).
// ---------------------------------------------------------------------------
__global__ __launch_bounds__(256, 2) void k2_mfma(const float* __restrict__ Z,
                                                  const ushort* __restrict__ Cbb,
                                                  const float* __restrict__ hn2g,
                                                  int4* __restrict__ cands) {
    __shared__ uint32_t Mld[64 * 129];   // [tok][slot*2+rank], stride 129 (pad)
    __shared__ uint32_t M2[64 * 34];     // [tok][seg][4] (key,pos), stride 34

    int tid  = threadIdx.x;
    int w    = tid >> 6;         // wave id = code quarter
    int lane = tid & 63;
    int c    = lane & 15, q = lane >> 4;
    int t0   = blockIdx.x * 64;

    // ---- A fragments: 4 mi x 8 ks, f32 -> bf16 in-register (loop-invariant)
    bf16x8 A[4][8];
    #pragma unroll
    for (int mi = 0; mi < 4; ++mi) {
        #pragma unroll
        for (int ks = 0; ks < 8; ++ks) {
            const float* zp = Z + (size_t)(t0 + mi * 16 + c) * CD + ks * 32 + q * 8;
            float4 f0 = *(const float4*)zp;
            float4 f1 = *(const float4*)(zp + 4);
            bf16x8 a;
            a[0] = (short)f2bf(f0.x); a[1] = (short)f2bf(f0.y);
            a[2] = (short)f2bf(f0.z); a[3] = (short)f2bf(f0.w);
            a[4] = (short)f2bf(f1.x); a[5] = (short)f2bf(f1.y);
            a[6] = (short)f2bf(f1.z); a[7] = (short)f2bf(f1.w);
            A[mi][ks] = a;
        }
    }

    int slot = w * 16 + c;
    // per-lane global B base: code = ct*64 + slot, k = ks*32 + q*8
    // byte addr = (code*256 + ks*32 + q*8)*2 = code*512 + q*16 + ks*64
    const char* bbase = (const char*)Cbb + (size_t)slot * 512 + q * 16;
    const char* b0p   = (slot == 0) ? (const char*)Cbb + 512 + q * 16 : bbase; // clamp code0->1
    const float* hbase = hn2g + slot;

    uint32_t K1[16], K2[16];
    #pragma unroll
    for (int i = 0; i < 16; ++i) { K1[i] = 0u; K2[i] = 0u; }

    bf16x8 B0[8], B1[8];
    float hv0, hv1;

    // prologue: tile 0 (clamped) -> B0
    #pragma unroll
    for (int ks = 0; ks < 8; ++ks)
        B0[ks] = *(const bf16x8*)(b0p + ks * 64);
    hv0 = (slot == 0) ? hn2g[1] : hbase[0];

    const char* bptr = bbase + 32768;   // tile 1 (ct>=1 never hits code 0)
    const float* hptr = hbase + 64;

    #define K2_COMPUTE(Bc, hvc, CT)                                            \
    {                                                                          \
        float nh = -(hvc);                                                     \
        floatx4 Cc[4];                                                         \
        _Pragma("unroll")                                                      \
        for (int mi = 0; mi < 4; ++mi) Cc[mi] = (floatx4){nh, nh, nh, nh};     \
        _Pragma("unroll")                                                      \
        for (int ks = 0; ks < 8; ++ks) {                                       \
            _Pragma("unroll")                                                  \
            for (int mi = 0; mi < 4; ++mi)                                     \
                Cc[mi] = __builtin_amdgcn_mfma_f32_16x16x32_bf16(              \
                    A[mi][ks], Bc[ks], Cc[mi], 0, 0, 0);                       \
        }                                                                      \
        _Pragma("unroll")                                                      \
        for (int mi = 0; mi < 4; ++mi) {                                       \
            _Pragma("unroll")                                                  \
            for (int r = 0; r < 4; ++r) {                                      \
                union { float f; uint32_t u; } uv; uv.f = Cc[mi][r];           \
                uint32_t key = (uv.u & 0xFFFFFFC0u) | (uint32_t)(CT);          \
                int i = mi * 4 + r;                                            \
                uint32_t lo = key < K1[i] ? key : K1[i];                       \
                K1[i] = key > K1[i] ? key : K1[i];                             \
                K2[i] = lo > K2[i] ? lo : K2[i];                               \
            }                                                                  \
        }                                                                      \
    }

    for (int ct = 0; ct < 64; ct += 2) {
        // prefetch ct+1 -> B1 (reads past cbb end on last iter land in wth ws
        // region — allocated, unused)
        #pragma unroll
        for (int ks = 0; ks < 8; ++ks)
            B1[ks] = *(const bf16x8*)(bptr + ks * 64);
        hv1 = *hptr;
        bptr += 32768; hptr += 64;

        K2_COMPUTE(B0, hv0, ct)

        // prefetch ct+2 -> B0
        #pragma unroll
        for (int ks = 0; ks < 8; ++ks)
            B0[ks] = *(const bf16x8*)(bptr + ks * 64);
        hv0 = *hptr;
        bptr += 32768; hptr += 64;

        K2_COMPUTE(B1, hv1, ct + 1)
    }
    #undef K2_COMPUTE

    // ---- merge stage 1: dump per-lane top-2 keys to LDS (padded stride)
    #pragma unroll
    for (int mi = 0; mi < 4; ++mi) {
        #pragma unroll
        for (int r = 0; r < 4; ++r) {
            int tok = mi * 16 + q * 4 + r;
            uint32_t* p = &Mld[tok * 129 + slot * 2];
            p[0] = K1[mi * 4 + r];
            p[1] = K2[mi * 4 + r];
        }
    }
    __syncthreads();

    // ---- merge stage 2: 4 threads/token, each scans 32 entries -> top-4
    {
        int tok = tid & 63, seg = tid >> 6;
        const uint32_t* row = &Mld[tok * 129 + seg * 32];
        uint32_t bk0 = 0, bk1 = 0, bk2 = 0, bk3 = 0;
        uint32_t bp0 = 0, bp1 = 0, bp2 = 0, bp3 = 0;
        for (int e = 0; e < 32; ++e) {
            uint32_t key = row[e];
            uint32_t pos = (uint32_t)(seg * 16 + (e >> 1));
            if (key > bk0) {
                bk3 = bk2; bp3 = bp2; bk2 = bk1; bp2 = bp1;
                bk1 = bk0; bp1 = bp0; bk0 = key; bp0 = pos;
            } else if (key > bk1) {
                bk3 = bk2; bp3 = bp2; bk2 = bk1; bp2 = bp1; bk1 = key; bp1 = pos;
            } else if (key > bk2) {
                bk3 = bk2; bp3 = bp2; bk2 = key; bp2 = pos;
            } else if (key > bk3) {
                bk3 = key; bp3 = pos;
            }
        }
        uint32_t* o = &M2[tok * 34 + seg * 8];
        o[0] = bk0; o[1] = bp0; o[2] = bk1; o[3] = bp1;
        o[4] = bk2; o[5] = bp2; o[6] = bk3; o[7] = bp3;
    }
    __syncthreads();

    // ---- merge stage 3: one thread/token, 16 candidates -> global top-4
    if (tid < 64) {
        int tok = tid;
        uint32_t bk0 = 0, bk1 = 0, bk2 = 0, bk3 = 0;
        uint32_t bp0 = 0, bp1 = 0, bp2 = 0, bp3 = 0;
        #pragma unroll
        for (int h = 0; h < 4; ++h) {
            #pragma unroll
            for (int j = 0; j < 4; ++j) {
                uint32_t key = M2[tok * 34 + h * 8 + j * 2];
                uint32_t pos = M2[tok * 34 + h * 8 + j * 2 + 1];
                if (key > bk0) {
                    bk3 = bk2; bp3 = bp2; bk2 = bk1; bp2 = bp1;
                    bk1 = bk0; bp1 = bp0; bk0 = key; bp0 = pos;
                } else if (key > bk1) {
                    bk3 = bk2; bp3 = bp2; bk2 = bk1; bp2 = bp1; bk1 = key; bp1 = pos;
                } else if (key > bk2) {
                    bk3 = bk2; bp3 = bp2; bk2 = key; bp2 = pos;
                } else if (key > bk3) {
                    bk3 = key; bp3 = pos;
                }
            }
        }
        int4 out;
        out.x = (int)(bk0 & 63u) * 64 + (int)bp0;
        out.y = (int)(bk1 & 63u) * 64 + (int)bp1;
        out.z = (int)(bk2 & 63u) * 64 + (int)bp2;
        out.w = (int)(bk3 & 63u) * 64 + (int)bp3;
        cands[t0 + tok] = out;
    }
}

// ---------------------------------------------------------------------------
// K3: f64 re-rank of 4 candidates (code 0 invalid; ties -> lowest index),
// write index (as float) + gather hard code. One wave per token.
// ---------------------------------------------------------------------------
__global__ __launch_bounds__(256) void k3_refine(const float4* __restrict__ Z,
                                                 const float4* __restrict__ Cb,
                                                 const int4* __restrict__ cands,
                                                 float* __restrict__ idxOut,
                                                 float4* __restrict__ hardOut) {
    int wid = threadIdx.x >> 6, lane = threadIdx.x & 63;
    int t = blockIdx.x * 4 + wid;
    int4 cd = cands[t];
    int cc[4] = {cd.x, cd.y, cd.z, cd.w};
    float4 z = Z[(size_t)t * Z_F4 + lane];
    double best = -1.0e300;
    int bi = NC;   // sentinel
    #pragma unroll
    for (int e = 0; e < 4; ++e) {
        int idx = cc[e];
        float4 cf = Cb[(size_t)idx * C_F4 + lane];
        double dot = (double)z.x*cf.x + (double)z.y*cf.y + (double)z.z*cf.z + (double)z.w*cf.w;
        double nrm = (double)cf.x*cf.x + (double)cf.y*cf.y + (double)cf.z*cf.z + (double)cf.w*cf.w;
        #pragma unroll
        for (int m = 32; m >= 1; m >>= 1) {
            dot += __shfl_xor(dot, m, 64);
            nrm += __shfl_xor(nrm, m, 64);
        }
        double s = dot - 0.5 * nrm;
        if (idx >= 1 && (s > best || (s == best && idx < bi))) { best = s; bi = idx; }
    }
    if (lane == 0) idxOut[t] = (float)bi;
    hardOut[(size_t)t * C_F4 + lane] = Cb[(size_t)bi * C_F4 + lane];
}

// ---------------------------------------------------------------------------
extern "C" void kernel_launch(void* const* d_in, const int* in_sizes, int n_in,
                              void* d_out, int out_size, void* d_ws, size_t ws_size,
                              hipStream_t stream) {
    const float* x  = (const float*)d_in[0];   // 32768 x 1024
    const float* cb = (const float*)d_in[1];   // 4096 x 256
    const float* w  = (const float*)d_in[2];   // 1024 x 256
    const float* bd = (const float*)d_in[3];   // 256

    float* zOut    = (float*)d_out;                    // 32768 x 256
    float* idxOut  = zOut + (size_t)NT * CD;           // 32768 (as float values)
    float* hardOut = idxOut + NT;                      // 32768 x 256

    float*  hn2   = (float*)d_ws;                            // 16 KB (+cands after: safe overread)
    int4*   cands = (int4*)((char*)d_ws + 16384);            // 512 KB
    ushort* cbb   = (ushort*)((char*)d_ws + 16384 + 524288); // 2 MB bf16 codebook (+wth after: safe overread)
    ushort* wth   = (ushort*)((char*)d_ws + 2637824);        // 512 KB bf16 W^T hi
    ushort* wtl   = (ushort*)((char*)d_ws + 3162112);        // 512 KB bf16 W^T lo

    k0_prep<<<NC / 4, 256, 0, stream>>>((const float4*)cb, hn2, cbb);
    k0b_wsplit<<<DM / 16, 256, 0, stream>>>((const float4*)w, wth, wtl);
    k1_gemm1<<<(NT / 128) * 2, 256, 0, stream>>>((const float4*)x, wth, wtl,
                                                 (float4*)zOut);
    k1b_norm<<<NT / 4, 256, 0, stream>>>((float4*)zOut, (const float4*)bd);
    k2_mfma<<<NT / 64, 256, 0, stream>>>(zOut, cbb, hn2, cands);
    k3_refine<<<NT / 4, 256, 0, stream>>>((const float4*)zOut, (const float4*)cb,
                                          cands, idxOut, (float4*)hardOut);
}

// Round 6
// 441.009 us; speedup vs baseline: 1.8550x; 1.0052x over previous
//
#include <hip/hip_runtime.h>
#include <math.h>
#include <stdint.h>

#define NT 32768
#define DM 1024
#define NC 4096
#define CD 256

#define X_F4 (DM/4)
#define W_F4 (CD/4)
#define Z_F4 (CD/4)
#define C_F4 (CD/4)

// extended-K codebook: 256 data + 2 (-hn2 hi/lo) + 14 zero pad = 272
#define CDE 272
#define CDE_B (CDE*2)        // 544 bytes per row
#define TILE_B (32*CDE_B)    // 17408 bytes per 32-code tile

typedef __attribute__((ext_vector_type(8))) short bf16x8;
typedef __attribute__((ext_vector_type(4))) float floatx4;
typedef __attribute__((ext_vector_type(16))) float floatx16;

__device__ __forceinline__ unsigned short f2bf(float f) {
    union { float f; uint32_t u; } v; v.f = f;
    uint32_t u = v.u;
    u += 0x7FFFu + ((u >> 16) & 1u);   // RN-even
    return (unsigned short)(u >> 16);
}

// split x into hi (truncated bf16) + lo (RNE bf16 of exact f32 residual)
__device__ __forceinline__ void split8(const float4 f0, const float4 f1,
                                       bf16x8& h, bf16x8& l) {
    float f[8] = {f0.x, f0.y, f0.z, f0.w, f1.x, f1.y, f1.z, f1.w};
    #pragma unroll
    for (int j = 0; j < 8; ++j) {
        union { float f; uint32_t u; } v; v.f = f[j];
        h[j] = (short)(v.u >> 16);
        union { uint32_t u; float f; } t; t.u = v.u & 0xFFFF0000u;
        l[j] = (short)f2bf(f[j] - t.f);
    }
}

// ---------------------------------------------------------------------------
// K0: build extended bf16 codebook cbb2[4096][272]:
//   k<256 : bf16(cb[code][k])
//   k=256 : trunc-bf16(2 - 0.5||c||^2)          (= -hn2, hi part)
//   k=257 : bf16 of residual                     (lo part)
//   k>=258: 0
// Score from MFMA with token-extension (1,1,0...) = z.c - hn2 in [0.5,3.0].
// ---------------------------------------------------------------------------
__global__ __launch_bounds__(256) void k0_prep(const float4* __restrict__ cb,
                                               ushort* __restrict__ cbb2) {
    int wid = threadIdx.x >> 6, lane = threadIdx.x & 63;
    int code = blockIdx.x * 4 + wid;
    float4 c = cb[(size_t)code * C_F4 + lane];
    ushort4 h;
    h.x = f2bf(c.x); h.y = f2bf(c.y); h.z = f2bf(c.z); h.w = f2bf(c.w);
    *(ushort4*)(cbb2 + (size_t)code * CDE + lane * 4) = h;
    float ss = c.x*c.x + c.y*c.y + c.z*c.z + c.w*c.w;
    #pragma unroll
    for (int m = 32; m >= 1; m >>= 1) ss += __shfl_xor(ss, m, 64);
    if (lane == 0) {
        float nh = 2.0f - 0.5f * ss;                    // = -hn2
        union { float f; uint32_t u; } v; v.f = nh;
        uint32_t uh = v.u & 0xFFFF0000u;
        union { uint32_t u; float f; } t; t.u = uh;
        ushort* p = cbb2 + (size_t)code * CDE + 256;
        p[0] = (ushort)(uh >> 16);
        p[1] = f2bf(nh - t.f);
        #pragma unroll
        for (int i = 2; i < 16; ++i) p[i] = 0;
    }
}

// ---------------------------------------------------------------------------
// K0b: W [1024][256] f32 -> transposed split-bf16 WT_hi/WT_lo [256][1024].
// ---------------------------------------------------------------------------
__global__ __launch_bounds__(256) void k0b_wsplit(const float4* __restrict__ W,
                                                  ushort* __restrict__ WTh,
                                                  ushort* __restrict__ WTl) {
    __shared__ float lds[16][260];
    int slab = blockIdx.x;              // 64 slabs of 16 k-rows
    int tid = threadIdx.x;
    #pragma unroll
    for (int jj = 0; jj < 4; ++jj) {
        int v = jj * 256 + tid;         // 0..1023
        int row = v >> 6, f4 = v & 63;
        float4 d = W[(size_t)(slab * 16 + row) * W_F4 + f4];
        *(float4*)&lds[row][f4 * 4] = d;
    }
    __syncthreads();
    int c = tid;                        // column (n) 0..255
    #pragma unroll
    for (int kb = 0; kb < 2; ++kb) {
        bf16x8 h, l;
        #pragma unroll
        for (int j = 0; j < 8; ++j) {
            float x = lds[kb * 8 + j][c];
            union { float f; uint32_t u; } v; v.f = x;
            h[j] = (short)(v.u >> 16);
            union { uint32_t u; float f; } t; t.u = v.u & 0xFFFF0000u;
            l[j] = (short)f2bf(x - t.f);
        }
        size_t off = (size_t)c * 1024 + slab * 16 + kb * 8;
        *(bf16x8*)(WTh + off) = h;
        *(bf16x8*)(WTl + off) = l;
    }
}

// ---------------------------------------------------------------------------
// K1: z_pre = x @ W_down via split-bf16 MFMA (Ootomo 3-term: hh + hl + lh).
// (unchanged — next round's target)
// ---------------------------------------------------------------------------
__global__ __launch_bounds__(256, 2) void k1_gemm1(const float4* __restrict__ X,
                                                   const ushort* __restrict__ WTh,
                                                   const ushort* __restrict__ WTl,
                                                   float4* __restrict__ Zp) {
    __shared__ __align__(16) char lds[65536];
    char* Ah = lds;              // 128 rows x 64 bf16 (swizzled chunks)
    char* Al = lds + 16384;
    char* Bh = lds + 32768;      // 128 cols(n) x 64 bf16
    char* Bl = lds + 49152;

    int tid  = threadIdx.x;
    int w    = tid >> 6, lane = tid & 63;
    int wm   = w >> 1, wn = w & 1;
    int c    = lane & 15, q = lane >> 4;
    int mb   = blockIdx.x >> 1, nb = blockIdx.x & 1;
    int m0   = mb * 128;
    int n0   = nb * 128;

    auto issue_loads = [&](int kt, float4* ga, bf16x8* gbh, bf16x8* gbl) {
        #pragma unroll
        for (int jj = 0; jj < 4; ++jj) {
            int v = jj * 256 + tid;           // 0..1023
            int row = v >> 3, ch = v & 7;
            const float4* p = X + (size_t)(m0 + row) * X_F4 + kt * 16 + ch * 2;
            ga[jj * 2]     = p[0];
            ga[jj * 2 + 1] = p[1];
        }
        #pragma unroll
        for (int jj = 0; jj < 4; ++jj) {
            int v = jj * 256 + tid;
            int col = v >> 3, ch = v & 7;
            size_t off = (size_t)(n0 + col) * 1024 + kt * 64 + ch * 8;
            gbh[jj] = *(const bf16x8*)(WTh + off);
            gbl[jj] = *(const bf16x8*)(WTl + off);
        }
    };
    auto write_lds = [&](const float4* ga, const bf16x8* gbh, const bf16x8* gbl) {
        #pragma unroll
        for (int jj = 0; jj < 4; ++jj) {
            int v = jj * 256 + tid;
            int row = v >> 3, ch = v & 7;
            bf16x8 h, l;
            split8(ga[jj * 2], ga[jj * 2 + 1], h, l);
            int off = row * 128 + ((ch ^ (row & 7)) << 4);
            *(bf16x8*)(Ah + off) = h;
            *(bf16x8*)(Al + off) = l;
        }
        #pragma unroll
        for (int jj = 0; jj < 4; ++jj) {
            int v = jj * 256 + tid;
            int col = v >> 3, ch = v & 7;
            int off = col * 128 + ((ch ^ (col & 7)) << 4);
            *(bf16x8*)(Bh + off) = gbh[jj];
            *(bf16x8*)(Bl + off) = gbl[jj];
        }
    };

    floatx4 acc[4][4];
    #pragma unroll
    for (int i = 0; i < 4; ++i)
        #pragma unroll
        for (int j = 0; j < 4; ++j) acc[i][j] = (floatx4){0.f, 0.f, 0.f, 0.f};

    float4 ga[8]; bf16x8 gbh[4], gbl[4];
    issue_loads(0, ga, gbh, gbl);
    write_lds(ga, gbh, gbl);

    for (int kt = 0; kt < 16; ++kt) {
        __syncthreads();
        if (kt < 15) issue_loads(kt + 1, ga, gbh, gbl);

        #pragma unroll
        for (int ks = 0; ks < 2; ++ks) {
            bf16x8 xh[4], xl[4], wh[4], wl[4];
            #pragma unroll
            for (int i = 0; i < 4; ++i) {
                int xrow = wm * 64 + i * 16 + c;
                int xoff = xrow * 128 + (((ks * 4 + q) ^ (xrow & 7)) << 4);
                xh[i] = *(const bf16x8*)(Ah + xoff);
                xl[i] = *(const bf16x8*)(Al + xoff);
                int wrow = wn * 64 + i * 16 + c;
                int woff = wrow * 128 + (((ks * 4 + q) ^ (wrow & 7)) << 4);
                wh[i] = *(const bf16x8*)(Bh + woff);
                wl[i] = *(const bf16x8*)(Bl + woff);
            }
            #pragma unroll
            for (int xi = 0; xi < 4; ++xi)
                #pragma unroll
                for (int ni = 0; ni < 4; ++ni) {
                    acc[xi][ni] = __builtin_amdgcn_mfma_f32_16x16x32_bf16(wh[ni], xh[xi], acc[xi][ni], 0, 0, 0);
                    acc[xi][ni] = __builtin_amdgcn_mfma_f32_16x16x32_bf16(wh[ni], xl[xi], acc[xi][ni], 0, 0, 0);
                    acc[xi][ni] = __builtin_amdgcn_mfma_f32_16x16x32_bf16(wl[ni], xh[xi], acc[xi][ni], 0, 0, 0);
                }
        }

        __syncthreads();
        if (kt < 15) write_lds(ga, gbh, gbl);
    }

    #pragma unroll
    for (int xi = 0; xi < 4; ++xi) {
        int tok = m0 + wm * 64 + xi * 16 + c;
        #pragma unroll
        for (int ni = 0; ni < 4; ++ni) {
            int nf4 = nb * 32 + wn * 16 + ni * 4 + q;
            float4 o;
            o.x = acc[xi][ni][0]; o.y = acc[xi][ni][1];
            o.z = acc[xi][ni][2]; o.w = acc[xi][ni][3];
            Zp[(size_t)tok * Z_F4 + nf4] = o;
        }
    }
}

// ---------------------------------------------------------------------------
// K1b: z = (z_pre + b) / (||z_pre + b|| + 1e-6) (unchanged)
// ---------------------------------------------------------------------------
__global__ __launch_bounds__(256) void k1b_norm(float4* __restrict__ Z,
                                                const float4* __restrict__ bias) {
    int wid = threadIdx.x >> 6, lane = threadIdx.x & 63;
    int t = blockIdx.x * 4 + wid;
    float4 b = bias[lane];
    float4 z = Z[(size_t)t * Z_F4 + lane];
    z.x += b.x; z.y += b.y; z.z += b.z; z.w += b.w;
    double ss = (double)z.x*z.x + (double)z.y*z.y + (double)z.z*z.z + (double)z.w*z.w;
    #pragma unroll
    for (int m = 32; m >= 1; m >>= 1) ss += __shfl_xor(ss, m, 64);
    float inv = 1.0f / ((float)sqrt(ss) + 1e-6f);
    z.x *= inv; z.y *= inv; z.z *= inv; z.w *= inv;
    Z[(size_t)t * Z_F4 + lane] = z;
}

// ---------------------------------------------------------------------------
// K2 v3: spill-free 32x32x16 MFMA scoring, tokens-resident / codes-streamed.
// Block = 4 waves x 32 tokens = 128 tokens; grid 256 (1 block/CU).
// B-operand (resident, 68 VGPR): 17 bf16x8 token frags (K=272: 256 data +
// [1,1] against the codebook's [-hn2_hi,-hn2_lo] extension + zero pad).
// A-operand (streamed): 32-code tile rows of cbb2 from L2, 17 b128/tile,
// register double-buffered. C/D: col=lane&31=token, row=code -> per lane
// ONE token, 16 codes/tile -> top-4 key state = 4 regs. No LDS in main
// loop; raw s_barrier every 16 tiles keeps waves aligned for L1 reuse.
// Keys: 21 score bits | ct(7) | reg(4). Code 0 clamped to 1 at tile 0.
// Exactness: each lane's 16 regs cover a fixed half of each tile's 32
// codes; union over the 2 lanes of a token = all codes; top-4 of two
// per-half top-4s = exact global top-4.
// ---------------------------------------------------------------------------
__global__ __launch_bounds__(256, 1) void k2_mfma(const float* __restrict__ Z,
                                                  const ushort* __restrict__ Cbb2,
                                                  int4* __restrict__ cands) {
    __shared__ uint32_t Mk[128][2][4];

    int tid  = threadIdx.x;
    int wm   = tid >> 6;         // token group
    int lane = tid & 63;
    int r    = lane & 31;
    int hi   = lane >> 5;        // k-half within 16
    int t0   = blockIdx.x * 128;

    // ---- resident token fragments (B-operand): col=r, k = f*16 + hi*8 + j
    bf16x8 Bt[17];
    #pragma unroll
    for (int f = 0; f < 16; ++f) {
        const float* zp = Z + (size_t)(t0 + wm * 32 + r) * CD + f * 16 + hi * 8;
        float4 f0 = *(const float4*)zp;
        float4 f1 = *(const float4*)(zp + 4);
        bf16x8 b;
        b[0] = (short)f2bf(f0.x); b[1] = (short)f2bf(f0.y);
        b[2] = (short)f2bf(f0.z); b[3] = (short)f2bf(f0.w);
        b[4] = (short)f2bf(f1.x); b[5] = (short)f2bf(f1.y);
        b[6] = (short)f2bf(f1.z); b[7] = (short)f2bf(f1.w);
        Bt[f] = b;
    }
    {
        bf16x8 b = (bf16x8){0, 0, 0, 0, 0, 0, 0, 0};
        if (hi == 0) { b[0] = (short)0x3F80; b[1] = (short)0x3F80; }  // 1.0,1.0
        Bt[16] = b;
    }

    // ---- per-lane streaming addresses (A-operand = codebook rows)
    int r0 = (r == 0) ? 1 : r;                        // clamp code 0 -> 1
    const char* abase   = (const char*)Cbb2;
    const char* ap_lane = abase + r * CDE_B + hi * 16;
    const char* ap0     = abase + r0 * CDE_B + hi * 16;

    uint32_t K1v = 0, K2v = 0, K3v = 0, K4v = 0;

    bf16x8 A0[17], A1[17];
    #pragma unroll
    for (int f = 0; f < 17; ++f) A0[f] = *(const bf16x8*)(ap0 + f * 32);

    const char* ap = ap_lane + TILE_B;                 // tile 1

    auto compute = [&](const bf16x8 (&Ax)[17], int ct) {
        floatx16 Cc;
        #pragma unroll
        for (int i = 0; i < 16; ++i) Cc[i] = 0.0f;
        #pragma unroll
        for (int f = 0; f < 17; ++f)
            Cc = __builtin_amdgcn_mfma_f32_32x32x16_bf16(Ax[f], Bt[f], Cc, 0, 0, 0);
        #pragma unroll
        for (int reg = 0; reg < 16; ++reg) {
            union { float f; uint32_t u; } uv; uv.f = Cc[reg];
            uint32_t k = (uv.u & 0xFFFFF800u) | ((uint32_t)ct << 4) | (uint32_t)reg;
            uint32_t t;
            t = k < K1v ? k : K1v;  K1v = k > K1v ? k : K1v;  k = t;
            t = k < K2v ? k : K2v;  K2v = k > K2v ? k : K2v;  k = t;
            t = k < K3v ? k : K3v;  K3v = k > K3v ? k : K3v;  k = t;
            K4v = k > K4v ? k : K4v;
        }
    };

    for (int ct = 0; ct < 128; ct += 2) {
        #pragma unroll
        for (int f = 0; f < 17; ++f) A1[f] = *(const bf16x8*)(ap + f * 32);
        ap += TILE_B;
        compute(A0, ct);
        const char* apn = (ct + 2 < 128) ? ap : ap_lane;   // clamp last prefetch
        #pragma unroll
        for (int f = 0; f < 17; ++f) A0[f] = *(const bf16x8*)(apn + f * 32);
        ap += TILE_B;
        compute(A1, ct + 1);
        if ((ct & 15) == 14) __builtin_amdgcn_s_barrier();  // wave alignment only
    }

    // ---- merge: per token 2 lanes x top-4 -> global top-4
    int lt = wm * 32 + r;
    Mk[lt][hi][0] = K1v; Mk[lt][hi][1] = K2v;
    Mk[lt][hi][2] = K3v; Mk[lt][hi][3] = K4v;
    __syncthreads();

    if (tid < 128) {
        uint32_t bk0 = 0, bk1 = 0, bk2 = 0, bk3 = 0;
        uint32_t be0 = 0, be1 = 0, be2 = 0, be3 = 0;
        #pragma unroll
        for (int e = 0; e < 8; ++e) {
            uint32_t key = Mk[tid][e >> 2][e & 3];
            if (key > bk0) {
                bk3 = bk2; be3 = be2; bk2 = bk1; be2 = be1;
                bk1 = bk0; be1 = be0; bk0 = key; be0 = (uint32_t)e;
            } else if (key > bk1) {
                bk3 = bk2; be3 = be2; bk2 = bk1; be2 = be1; bk1 = key; be1 = (uint32_t)e;
            } else if (key > bk2) {
                bk3 = bk2; be3 = be2; bk2 = key; be2 = (uint32_t)e;
            } else if (key > bk3) {
                bk3 = key; be3 = (uint32_t)e;
            }
        }
        auto dec = [&](uint32_t key, uint32_t e) -> int {
            int ct = (int)((key >> 4) & 127u);
            int rg = (int)(key & 15u);
            int row = (rg & 3) + 8 * (rg >> 2) + 4 * (int)(e >> 2);
            int code = ct * 32 + row;
            return code < 1 ? 1 : code;
        };
        int4 out;
        out.x = dec(bk0, be0); out.y = dec(bk1, be1);
        out.z = dec(bk2, be2); out.w = dec(bk3, be3);
        cands[t0 + tid] = out;
    }
}

// ---------------------------------------------------------------------------
// K3: f64 re-rank of 4 candidates (code 0 invalid; ties -> lowest index),
// write index (as float) + gather hard code. One wave per token.
// ---------------------------------------------------------------------------
__global__ __launch_bounds__(256) void k3_refine(const float4* __restrict__ Z,
                                                 const float4* __restrict__ Cb,
                                                 const int4* __restrict__ cands,
                                                 float* __restrict__ idxOut,
                                                 float4* __restrict__ hardOut) {
    int wid = threadIdx.x >> 6, lane = threadIdx.x & 63;
    int t = blockIdx.x * 4 + wid;
    int4 cd = cands[t];
    int cc[4] = {cd.x, cd.y, cd.z, cd.w};
    float4 z = Z[(size_t)t * Z_F4 + lane];
    double best = -1.0e300;
    int bi = NC;   // sentinel
    #pragma unroll
    for (int e = 0; e < 4; ++e) {
        int idx = cc[e];
        float4 cf = Cb[(size_t)idx * C_F4 + lane];
        double dot = (double)z.x*cf.x + (double)z.y*cf.y + (double)z.z*cf.z + (double)z.w*cf.w;
        double nrm = (double)cf.x*cf.x + (double)cf.y*cf.y + (double)cf.z*cf.z + (double)cf.w*cf.w;
        #pragma unroll
        for (int m = 32; m >= 1; m >>= 1) {
            dot += __shfl_xor(dot, m, 64);
            nrm += __shfl_xor(nrm, m, 64);
        }
        double s = dot - 0.5 * nrm;
        if (idx >= 1 && (s > best || (s == best && idx < bi))) { best = s; bi = idx; }
    }
    if (lane == 0) idxOut[t] = (float)bi;
    hardOut[(size_t)t * C_F4 + lane] = Cb[(size_t)bi * C_F4 + lane];
}

// ---------------------------------------------------------------------------
extern "C" void kernel_launch(void* const* d_in, const int* in_sizes, int n_in,
                              void* d_out, int out_size, void* d_ws, size_t ws_size,
                              hipStream_t stream) {
    const float* x  = (const float*)d_in[0];   // 32768 x 1024
    const float* cb = (const float*)d_in[1];   // 4096 x 256
    const float* w  = (const float*)d_in[2];   // 1024 x 256
    const float* bd = (const float*)d_in[3];   // 256

    float* zOut    = (float*)d_out;                    // 32768 x 256
    float* idxOut  = zOut + (size_t)NT * CD;           // 32768 (as float values)
    float* hardOut = idxOut + NT;                      // 32768 x 256

    int4*   cands = (int4*)d_ws;                             // 512 KB
    ushort* cbb2  = (ushort*)((char*)d_ws + 524288);         // 4096*272*2 = 2,228,224 B
    ushort* wth   = (ushort*)((char*)d_ws + 2752512);        // 512 KB bf16 W^T hi
    ushort* wtl   = (ushort*)((char*)d_ws + 3276800);        // 512 KB bf16 W^T lo

    k0_prep<<<NC / 4, 256, 0, stream>>>((const float4*)cb, cbb2);
    k0b_wsplit<<<DM / 16, 256, 0, stream>>>((const float4*)w, wth, wtl);
    k1_gemm1<<<(NT / 128) * 2, 256, 0, stream>>>((const float4*)x, wth, wtl,
                                                 (float4*)zOut);
    k1b_norm<<<NT / 4, 256, 0, stream>>>((float4*)zOut, (const float4*)bd);
    k2_mfma<<<NT / 128, 256, 0, stream>>>(zOut, cbb2, cands);
    k3_refine<<<NT / 4, 256, 0, stream>>>((const float4*)zOut, (const float4*)cb,
                                          cands, idxOut, (float4*)hardOut);
}

// Round 7
// 392.198 us; speedup vs baseline: 2.0858x; 1.1245x over previous
//
#include <hip/hip_runtime.h>
#include <math.h>
#include <stdint.h>

#define NT 32768
#define DM 1024
#define NC 4096
#define CD 256

#define X_F4 (DM/4)
#define W_F4 (CD/4)
#define Z_F4 (CD/4)
#define C_F4 (CD/4)

// fragment-ordered extended codebook: 128 tiles x 17 frag-KB
// addr(ct, f, lane) = ct*TILE_B + f*1024 + lane*16, lane = (hi<<5)|row
// f<16: data k-slice f*16 + hi*8 ..+8 of code ct*32+row
// f=16: hi=0 -> [-hn2_hi, -hn2_lo, 0...]; hi=1 -> zeros
#define TILE_B 17408

typedef __attribute__((ext_vector_type(8))) short bf16x8;
typedef __attribute__((ext_vector_type(4))) float floatx4;
typedef __attribute__((ext_vector_type(16))) float floatx16;

__device__ __forceinline__ unsigned short f2bf(float f) {
    union { float f; uint32_t u; } v; v.f = f;
    uint32_t u = v.u;
    u += 0x7FFFu + ((u >> 16) & 1u);   // RN-even
    return (unsigned short)(u >> 16);
}

// split x into hi (truncated bf16) + lo (RNE bf16 of exact f32 residual)
__device__ __forceinline__ void split8(const float4 f0, const float4 f1,
                                       bf16x8& h, bf16x8& l) {
    float f[8] = {f0.x, f0.y, f0.z, f0.w, f1.x, f1.y, f1.z, f1.w};
    #pragma unroll
    for (int j = 0; j < 8; ++j) {
        union { float f; uint32_t u; } v; v.f = f[j];
        h[j] = (short)(v.u >> 16);
        union { uint32_t u; float f; } t; t.u = v.u & 0xFFFF0000u;
        l[j] = (short)f2bf(f[j] - t.f);
    }
}

// ---------------------------------------------------------------------------
// K0: build fragment-ordered extended bf16 codebook (see layout above).
// 256 threads = 4 waves, 2 codes per wave (32 lanes each). Lane handles one
// 16B fragment (f = fr>>1, hi = fr&1); ss reduced over the 32-lane group.
// ---------------------------------------------------------------------------
__global__ __launch_bounds__(256) void k0_prep(const float4* __restrict__ cb,
                                               ushort* __restrict__ cbb2) {
    int tid = threadIdx.x;
    int l = tid & 63, wid = tid >> 6;
    int code = blockIdx.x * 8 + wid * 2 + (l >> 5);
    int fr = l & 31, f = fr >> 1, hi = fr & 1;
    const float4* p = cb + (size_t)code * C_F4 + f * 4 + hi * 2;
    float4 f0 = p[0], f1 = p[1];
    bf16x8 h;
    h[0] = (short)f2bf(f0.x); h[1] = (short)f2bf(f0.y);
    h[2] = (short)f2bf(f0.z); h[3] = (short)f2bf(f0.w);
    h[4] = (short)f2bf(f1.x); h[5] = (short)f2bf(f1.y);
    h[6] = (short)f2bf(f1.z); h[7] = (short)f2bf(f1.w);
    float ss = f0.x*f0.x + f0.y*f0.y + f0.z*f0.z + f0.w*f0.w
             + f1.x*f1.x + f1.y*f1.y + f1.z*f1.z + f1.w*f1.w;
    #pragma unroll
    for (int m = 16; m >= 1; m >>= 1) ss += __shfl_xor(ss, m, 64);
    int ct = code >> 5, r = code & 31;
    char* base = (char*)cbb2 + (size_t)ct * TILE_B;
    *(bf16x8*)(base + f * 1024 + (((hi << 5) | r) << 4)) = h;
    if (fr == 0) {
        float nh = 2.0f - 0.5f * ss;                   // = -hn2
        union { float f; uint32_t u; } v; v.f = nh;
        uint32_t uh = v.u & 0xFFFF0000u;
        union { uint32_t u; float f; } t; t.u = uh;
        bf16x8 e = (bf16x8){0, 0, 0, 0, 0, 0, 0, 0};
        e[0] = (short)(uh >> 16);
        e[1] = (short)f2bf(nh - t.f);
        *(bf16x8*)(base + 16 * 1024 + (r << 4)) = e;
    } else if (fr == 1) {
        bf16x8 z = (bf16x8){0, 0, 0, 0, 0, 0, 0, 0};
        *(bf16x8*)(base + 16 * 1024 + ((32 | r) << 4)) = z;
    }
}

// ---------------------------------------------------------------------------
// K0b: W [1024][256] f32 -> transposed split-bf16 WT_hi/WT_lo [256][1024].
// ---------------------------------------------------------------------------
__global__ __launch_bounds__(256) void k0b_wsplit(const float4* __restrict__ W,
                                                  ushort* __restrict__ WTh,
                                                  ushort* __restrict__ WTl) {
    __shared__ float lds[16][260];
    int slab = blockIdx.x;              // 64 slabs of 16 k-rows
    int tid = threadIdx.x;
    #pragma unroll
    for (int jj = 0; jj < 4; ++jj) {
        int v = jj * 256 + tid;         // 0..1023
        int row = v >> 6, f4 = v & 63;
        float4 d = W[(size_t)(slab * 16 + row) * W_F4 + f4];
        *(float4*)&lds[row][f4 * 4] = d;
    }
    __syncthreads();
    int c = tid;                        // column (n) 0..255
    #pragma unroll
    for (int kb = 0; kb < 2; ++kb) {
        bf16x8 h, l;
        #pragma unroll
        for (int j = 0; j < 8; ++j) {
            float x = lds[kb * 8 + j][c];
            union { float f; uint32_t u; } v; v.f = x;
            h[j] = (short)(v.u >> 16);
            union { uint32_t u; float f; } t; t.u = v.u & 0xFFFF0000u;
            l[j] = (short)f2bf(x - t.f);
        }
        size_t off = (size_t)c * 1024 + slab * 16 + kb * 8;
        *(bf16x8*)(WTh + off) = h;
        *(bf16x8*)(WTl + off) = l;
    }
}

// ---------------------------------------------------------------------------
// K1: z_pre = x @ W_down via split-bf16 MFMA (Ootomo 3-term: hh + hl + lh).
// (unchanged — next round's target)
// ---------------------------------------------------------------------------
__global__ __launch_bounds__(256, 2) void k1_gemm1(const float4* __restrict__ X,
                                                   const ushort* __restrict__ WTh,
                                                   const ushort* __restrict__ WTl,
                                                   float4* __restrict__ Zp) {
    __shared__ __align__(16) char lds[65536];
    char* Ah = lds;              // 128 rows x 64 bf16 (swizzled chunks)
    char* Al = lds + 16384;
    char* Bh = lds + 32768;      // 128 cols(n) x 64 bf16
    char* Bl = lds + 49152;

    int tid  = threadIdx.x;
    int w    = tid >> 6, lane = tid & 63;
    int wm   = w >> 1, wn = w & 1;
    int c    = lane & 15, q = lane >> 4;
    int mb   = blockIdx.x >> 1, nb = blockIdx.x & 1;
    int m0   = mb * 128;
    int n0   = nb * 128;

    auto issue_loads = [&](int kt, float4* ga, bf16x8* gbh, bf16x8* gbl) {
        #pragma unroll
        for (int jj = 0; jj < 4; ++jj) {
            int v = jj * 256 + tid;           // 0..1023
            int row = v >> 3, ch = v & 7;
            const float4* p = X + (size_t)(m0 + row) * X_F4 + kt * 16 + ch * 2;
            ga[jj * 2]     = p[0];
            ga[jj * 2 + 1] = p[1];
        }
        #pragma unroll
        for (int jj = 0; jj < 4; ++jj) {
            int v = jj * 256 + tid;
            int col = v >> 3, ch = v & 7;
            size_t off = (size_t)(n0 + col) * 1024 + kt * 64 + ch * 8;
            gbh[jj] = *(const bf16x8*)(WTh + off);
            gbl[jj] = *(const bf16x8*)(WTl + off);
        }
    };
    auto write_lds = [&](const float4* ga, const bf16x8* gbh, const bf16x8* gbl) {
        #pragma unroll
        for (int jj = 0; jj < 4; ++jj) {
            int v = jj * 256 + tid;
            int row = v >> 3, ch = v & 7;
            bf16x8 h, l;
            split8(ga[jj * 2], ga[jj * 2 + 1], h, l);
            int off = row * 128 + ((ch ^ (row & 7)) << 4);
            *(bf16x8*)(Ah + off) = h;
            *(bf16x8*)(Al + off) = l;
        }
        #pragma unroll
        for (int jj = 0; jj < 4; ++jj) {
            int v = jj * 256 + tid;
            int col = v >> 3, ch = v & 7;
            int off = col * 128 + ((ch ^ (col & 7)) << 4);
            *(bf16x8*)(Bh + off) = gbh[jj];
            *(bf16x8*)(Bl + off) = gbl[jj];
        }
    };

    floatx4 acc[4][4];
    #pragma unroll
    for (int i = 0; i < 4; ++i)
        #pragma unroll
        for (int j = 0; j < 4; ++j) acc[i][j] = (floatx4){0.f, 0.f, 0.f, 0.f};

    float4 ga[8]; bf16x8 gbh[4], gbl[4];
    issue_loads(0, ga, gbh, gbl);
    write_lds(ga, gbh, gbl);

    for (int kt = 0; kt < 16; ++kt) {
        __syncthreads();
        if (kt < 15) issue_loads(kt + 1, ga, gbh, gbl);

        #pragma unroll
        for (int ks = 0; ks < 2; ++ks) {
            bf16x8 xh[4], xl[4], wh[4], wl[4];
            #pragma unroll
            for (int i = 0; i < 4; ++i) {
                int xrow = wm * 64 + i * 16 + c;
                int xoff = xrow * 128 + (((ks * 4 + q) ^ (xrow & 7)) << 4);
                xh[i] = *(const bf16x8*)(Ah + xoff);
                xl[i] = *(const bf16x8*)(Al + xoff);
                int wrow = wn * 64 + i * 16 + c;
                int woff = wrow * 128 + (((ks * 4 + q) ^ (wrow & 7)) << 4);
                wh[i] = *(const bf16x8*)(Bh + woff);
                wl[i] = *(const bf16x8*)(Bl + woff);
            }
            #pragma unroll
            for (int xi = 0; xi < 4; ++xi)
                #pragma unroll
                for (int ni = 0; ni < 4; ++ni) {
                    acc[xi][ni] = __builtin_amdgcn_mfma_f32_16x16x32_bf16(wh[ni], xh[xi], acc[xi][ni], 0, 0, 0);
                    acc[xi][ni] = __builtin_amdgcn_mfma_f32_16x16x32_bf16(wh[ni], xl[xi], acc[xi][ni], 0, 0, 0);
                    acc[xi][ni] = __builtin_amdgcn_mfma_f32_16x16x32_bf16(wl[ni], xh[xi], acc[xi][ni], 0, 0, 0);
                }
        }

        __syncthreads();
        if (kt < 15) write_lds(ga, gbh, gbl);
    }

    #pragma unroll
    for (int xi = 0; xi < 4; ++xi) {
        int tok = m0 + wm * 64 + xi * 16 + c;
        #pragma unroll
        for (int ni = 0; ni < 4; ++ni) {
            int nf4 = nb * 32 + wn * 16 + ni * 4 + q;
            float4 o;
            o.x = acc[xi][ni][0]; o.y = acc[xi][ni][1];
            o.z = acc[xi][ni][2]; o.w = acc[xi][ni][3];
            Zp[(size_t)tok * Z_F4 + nf4] = o;
        }
    }
}

// ---------------------------------------------------------------------------
// K1b: z = (z_pre + b) / (||z_pre + b|| + 1e-6) (unchanged)
// ---------------------------------------------------------------------------
__global__ __launch_bounds__(256) void k1b_norm(float4* __restrict__ Z,
                                                const float4* __restrict__ bias) {
    int wid = threadIdx.x >> 6, lane = threadIdx.x & 63;
    int t = blockIdx.x * 4 + wid;
    float4 b = bias[lane];
    float4 z = Z[(size_t)t * Z_F4 + lane];
    z.x += b.x; z.y += b.y; z.z += b.z; z.w += b.w;
    double ss = (double)z.x*z.x + (double)z.y*z.y + (double)z.z*z.z + (double)z.w*z.w;
    #pragma unroll
    for (int m = 32; m >= 1; m >>= 1) ss += __shfl_xor(ss, m, 64);
    float inv = 1.0f / ((float)sqrt(ss) + 1e-6f);
    z.x *= inv; z.y *= inv; z.z *= inv; z.w *= inv;
    Z[(size_t)t * Z_F4 + lane] = z;
}

// ---------------------------------------------------------------------------
// K2 v4: occupancy + coalesced-stream scoring.
// Block = 256 threads = 4 waves = 2 token-groups (wm) x 2 code-halves (wc);
// 64 tokens/block, grid 512 -> 2 blocks/CU = 8 waves/CU = 2 waves/SIMD
// (v3 was 1/SIMD -> fully exposed latency). Each wave: 32 resident tokens
// (B-operand, 68 VGPR) x 64 codebook tiles streamed as the A-operand from
// the fragment-ordered cbb2 — every A-load is a contiguous, fully-coalesced
// 1KB dwordx4 (v3 was stride-544 scatter). Register double-buffer A0/A1.
// Running top-4 per lane via v_fmed3 (keys are positive floats: f32 order
// = u32 order): 4 sort ops + 1 and_or per reg (v3: ~10).
// Keys: 21 score bits | ct(7) | reg(4). Exact: (wc,hi) sources cover
// disjoint code sets; merge of per-source top-4s = exact global top-4.
// ---------------------------------------------------------------------------
__global__ __launch_bounds__(256, 2) void k2_mfma(const float* __restrict__ Z,
                                                  const ushort* __restrict__ Cbb2,
                                                  int4* __restrict__ cands) {
    __shared__ uint32_t Mk[64][4][4];   // [token][wc*2+hi][rank]

    int tid  = threadIdx.x;
    int w    = tid >> 6;
    int wm   = w >> 1;           // token group
    int wc   = w & 1;            // code half
    int lane = tid & 63;
    int r    = lane & 31;
    int hi   = lane >> 5;
    int t0   = blockIdx.x * 64;

    // ---- resident token fragments (B-operand): col=r, k = f*16 + hi*8 + j
    bf16x8 Bt[17];
    #pragma unroll
    for (int f = 0; f < 16; ++f) {
        const float* zp = Z + (size_t)(t0 + wm * 32 + r) * CD + f * 16 + hi * 8;
        float4 f0 = *(const float4*)zp;
        float4 f1 = *(const float4*)(zp + 4);
        bf16x8 b;
        b[0] = (short)f2bf(f0.x); b[1] = (short)f2bf(f0.y);
        b[2] = (short)f2bf(f0.z); b[3] = (short)f2bf(f0.w);
        b[4] = (short)f2bf(f1.x); b[5] = (short)f2bf(f1.y);
        b[6] = (short)f2bf(f1.z); b[7] = (short)f2bf(f1.w);
        Bt[f] = b;
    }
    {
        bf16x8 b = (bf16x8){0, 0, 0, 0, 0, 0, 0, 0};
        if (hi == 0) { b[0] = (short)0x3F80; b[1] = (short)0x3F80; }  // 1.0,1.0
        Bt[16] = b;
    }

    // ---- streaming A addresses: lane IS the fragment slot (coalesced)
    const char* half = (const char*)Cbb2 + (size_t)(wc * 64) * TILE_B;
    int l0 = (wc == 0 && r == 0) ? (lane + 1) : lane;  // clamp code0 slot @tile0
    const char* ap0 = half + l0 * 16;
    const char* apL = half + lane * 16;

    float K1f = 0.0f, K2f = 0.0f, K3f = 0.0f, K4f = 0.0f;

    bf16x8 A0[17], A1[17];
    #pragma unroll
    for (int f = 0; f < 17; ++f) A0[f] = *(const bf16x8*)(ap0 + f * 1024);

    const char* ap = apL + TILE_B;                     // next tile

    auto compute = [&](const bf16x8 (&Ax)[17], int ct) {
        floatx16 Cc;
        #pragma unroll
        for (int i = 0; i < 16; ++i) Cc[i] = 0.0f;
        #pragma unroll
        for (int f = 0; f < 17; ++f)
            Cc = __builtin_amdgcn_mfma_f32_32x32x16_bf16(Ax[f], Bt[f], Cc, 0, 0, 0);
        #pragma unroll
        for (int reg = 0; reg < 16; ++reg) {
            union { float f; uint32_t u; } uv; uv.f = Cc[reg];
            uint32_t ku = (uv.u & 0xFFFFF800u) | ((uint32_t)ct << 4) | (uint32_t)reg;
            union { uint32_t u; float f; } kv; kv.u = ku;
            float k = kv.f;
            K4f = __builtin_amdgcn_fmed3f(K3f, K4f, k);
            K3f = __builtin_amdgcn_fmed3f(K2f, K3f, k);
            K2f = __builtin_amdgcn_fmed3f(K1f, K2f, k);
            K1f = fmaxf(K1f, k);
        }
    };

    for (int ctl = 0; ctl < 64; ctl += 2) {
        #pragma unroll
        for (int f = 0; f < 17; ++f) A1[f] = *(const bf16x8*)(ap + f * 1024);
        ap += TILE_B;
        compute(A0, wc * 64 + ctl);
        const char* apn = (ctl + 2 < 64) ? ap : apL;   // clamp last prefetch
        #pragma unroll
        for (int f = 0; f < 17; ++f) A0[f] = *(const bf16x8*)(apn + f * 1024);
        ap += TILE_B;
        compute(A1, wc * 64 + ctl + 1);
        if ((ctl & 15) == 14) __builtin_amdgcn_s_barrier();  // wave alignment
    }

    // ---- merge: per token 4 sources (wc x hi) x top-4 -> global top-4
    {
        int lt = wm * 32 + r, src = wc * 2 + hi;
        union { float f; uint32_t u; } a, b, c, d;
        a.f = K1f; b.f = K2f; c.f = K3f; d.f = K4f;
        Mk[lt][src][0] = a.u; Mk[lt][src][1] = b.u;
        Mk[lt][src][2] = c.u; Mk[lt][src][3] = d.u;
    }
    __syncthreads();

    if (tid < 64) {
        uint32_t bk0 = 0, bk1 = 0, bk2 = 0, bk3 = 0;
        uint32_t be0 = 0, be1 = 0, be2 = 0, be3 = 0;
        #pragma unroll
        for (int s = 0; s < 4; ++s) {
            #pragma unroll
            for (int j = 0; j < 4; ++j) {
                uint32_t key = Mk[tid][s][j];
                uint32_t e = (uint32_t)s;           // hi = s&1
                if (key > bk0) {
                    bk3 = bk2; be3 = be2; bk2 = bk1; be2 = be1;
                    bk1 = bk0; be1 = be0; bk0 = key; be0 = e;
                } else if (key > bk1) {
                    bk3 = bk2; be3 = be2; bk2 = bk1; be2 = be1; bk1 = key; be1 = e;
                } else if (key > bk2) {
                    bk3 = bk2; be3 = be2; bk2 = key; be2 = e;
                } else if (key > bk3) {
                    bk3 = key; be3 = e;
                }
            }
        }
        auto dec = [&](uint32_t key, uint32_t e) -> int {
            int ct = (int)((key >> 4) & 127u);
            int rg = (int)(key & 15u);
            int row = (rg & 3) + 8 * (rg >> 2) + 4 * (int)(e & 1);
            int code = ct * 32 + row;
            return code < 1 ? 1 : code;
        };
        int4 out;
        out.x = dec(bk0, be0); out.y = dec(bk1, be1);
        out.z = dec(bk2, be2); out.w = dec(bk3, be3);
        cands[t0 + tid] = out;
    }
}

// ---------------------------------------------------------------------------
// K3: f64 re-rank of 4 candidates (code 0 invalid; ties -> lowest index),
// write index (as float) + gather hard code. One wave per token.
// ---------------------------------------------------------------------------
__global__ __launch_bounds__(256) void k3_refine(const float4* __restrict__ Z,
                                                 const float4* __restrict__ Cb,
                                                 const int4* __restrict__ cands,
                                                 float* __restrict__ idxOut,
                                                 float4* __restrict__ hardOut) {
    int wid = threadIdx.x >> 6, lane = threadIdx.x & 63;
    int t = blockIdx.x * 4 + wid;
    int4 cd = cands[t];
    int cc[4] = {cd.x, cd.y, cd.z, cd.w};
    float4 z = Z[(size_t)t * Z_F4 + lane];
    double best = -1.0e300;
    int bi = NC;   // sentinel
    #pragma unroll
    for (int e = 0; e < 4; ++e) {
        int idx = cc[e];
        float4 cf = Cb[(size_t)idx * C_F4 + lane];
        double dot = (double)z.x*cf.x + (double)z.y*cf.y + (double)z.z*cf.z + (double)z.w*cf.w;
        double nrm = (double)cf.x*cf.x + (double)cf.y*cf.y + (double)cf.z*cf.z + (double)cf.w*cf.w;
        #pragma unroll
        for (int m = 32; m >= 1; m >>= 1) {
            dot += __shfl_xor(dot, m, 64);
            nrm += __shfl_xor(nrm, m, 64);
        }
        double s = dot - 0.5 * nrm;
        if (idx >= 1 && (s > best || (s == best && idx < bi))) { best = s; bi = idx; }
    }
    if (lane == 0) idxOut[t] = (float)bi;
    hardOut[(size_t)t * C_F4 + lane] = Cb[(size_t)bi * C_F4 + lane];
}

// ---------------------------------------------------------------------------
extern "C" void kernel_launch(void* const* d_in, const int* in_sizes, int n_in,
                              void* d_out, int out_size, void* d_ws, size_t ws_size,
                              hipStream_t stream) {
    const float* x  = (const float*)d_in[0];   // 32768 x 1024
    const float* cb = (const float*)d_in[1];   // 4096 x 256
    const float* w  = (const float*)d_in[2];   // 1024 x 256
    const float* bd = (const float*)d_in[3];   // 256

    float* zOut    = (float*)d_out;                    // 32768 x 256
    float* idxOut  = zOut + (size_t)NT * CD;           // 32768 (as float values)
    float* hardOut = idxOut + NT;                      // 32768 x 256

    int4*   cands = (int4*)d_ws;                             // 512 KB
    ushort* cbb2  = (ushort*)((char*)d_ws + 524288);         // 128*17408 = 2,228,224 B
    ushort* wth   = (ushort*)((char*)d_ws + 2752512);        // 512 KB bf16 W^T hi
    ushort* wtl   = (ushort*)((char*)d_ws + 3276800);        // 512 KB bf16 W^T lo

    k0_prep<<<NC / 8, 256, 0, stream>>>((const float4*)cb, cbb2);
    k0b_wsplit<<<DM / 16, 256, 0, stream>>>((const float4*)w, wth, wtl);
    k1_gemm1<<<(NT / 128) * 2, 256, 0, stream>>>((const float4*)x, wth, wtl,
                                                 (float4*)zOut);
    k1b_norm<<<NT / 4, 256, 0, stream>>>((float4*)zOut, (const float4*)bd);
    k2_mfma<<<NT / 64, 256, 0, stream>>>(zOut, cbb2, cands);
    k3_refine<<<NT / 4, 256, 0, stream>>>((const float4*)zOut, (const float4*)cb,
                                          cands, idxOut, (float4*)hardOut);
}

// Round 8
// 391.885 us; speedup vs baseline: 2.0875x; 1.0008x over previous
//
#include <hip/hip_runtime.h>
#include <math.h>
#include <stdint.h>

#define NT 32768
#define DM 1024
#define NC 4096
#define CD 256

#define X_F4 (DM/4)
#define W_F4 (CD/4)
#define Z_F4 (CD/4)
#define C_F4 (CD/4)

// fragment-ordered extended codebook: 128 tiles x 17 frag-KB
// addr(ct, f, lane) = ct*TILE_B + f*1024 + lane*16, lane = (hi<<5)|row
// f<16: data k-slice f*16 + hi*8 ..+8 of code ct*32+row
// f=16: hi=0 -> [-hn2_hi, -hn2_lo, 0...]; hi=1 -> zeros
#define TILE_B 17408

typedef __attribute__((ext_vector_type(8))) short bf16x8;
typedef __attribute__((ext_vector_type(4))) float floatx4;
typedef __attribute__((ext_vector_type(16))) float floatx16;

__device__ __forceinline__ unsigned short f2bf(float f) {
    union { float f; uint32_t u; } v; v.f = f;
    uint32_t u = v.u;
    u += 0x7FFFu + ((u >> 16) & 1u);   // RN-even
    return (unsigned short)(u >> 16);
}

// split x into hi (truncated bf16) + lo (RNE bf16 of exact f32 residual)
__device__ __forceinline__ void split8(const float4 f0, const float4 f1,
                                       bf16x8& h, bf16x8& l) {
    float f[8] = {f0.x, f0.y, f0.z, f0.w, f1.x, f1.y, f1.z, f1.w};
    #pragma unroll
    for (int j = 0; j < 8; ++j) {
        union { float f; uint32_t u; } v; v.f = f[j];
        h[j] = (short)(v.u >> 16);
        union { uint32_t u; float f; } t; t.u = v.u & 0xFFFF0000u;
        l[j] = (short)f2bf(f[j] - t.f);
    }
}

// ---------------------------------------------------------------------------
// K0: build fragment-ordered extended bf16 codebook (see layout above).
// ---------------------------------------------------------------------------
__global__ __launch_bounds__(256) void k0_prep(const float4* __restrict__ cb,
                                               ushort* __restrict__ cbb2) {
    int tid = threadIdx.x;
    int l = tid & 63, wid = tid >> 6;
    int code = blockIdx.x * 8 + wid * 2 + (l >> 5);
    int fr = l & 31, f = fr >> 1, hi = fr & 1;
    const float4* p = cb + (size_t)code * C_F4 + f * 4 + hi * 2;
    float4 f0 = p[0], f1 = p[1];
    bf16x8 h;
    h[0] = (short)f2bf(f0.x); h[1] = (short)f2bf(f0.y);
    h[2] = (short)f2bf(f0.z); h[3] = (short)f2bf(f0.w);
    h[4] = (short)f2bf(f1.x); h[5] = (short)f2bf(f1.y);
    h[6] = (short)f2bf(f1.z); h[7] = (short)f2bf(f1.w);
    float ss = f0.x*f0.x + f0.y*f0.y + f0.z*f0.z + f0.w*f0.w
             + f1.x*f1.x + f1.y*f1.y + f1.z*f1.z + f1.w*f1.w;
    #pragma unroll
    for (int m = 16; m >= 1; m >>= 1) ss += __shfl_xor(ss, m, 64);
    int ct = code >> 5, r = code & 31;
    char* base = (char*)cbb2 + (size_t)ct * TILE_B;
    *(bf16x8*)(base + f * 1024 + (((hi << 5) | r) << 4)) = h;
    if (fr == 0) {
        float nh = 2.0f - 0.5f * ss;                   // = -hn2
        union { float f; uint32_t u; } v; v.f = nh;
        uint32_t uh = v.u & 0xFFFF0000u;
        union { uint32_t u; float f; } t; t.u = uh;
        bf16x8 e = (bf16x8){0, 0, 0, 0, 0, 0, 0, 0};
        e[0] = (short)(uh >> 16);
        e[1] = (short)f2bf(nh - t.f);
        *(bf16x8*)(base + 16 * 1024 + (r << 4)) = e;
    } else if (fr == 1) {
        bf16x8 z = (bf16x8){0, 0, 0, 0, 0, 0, 0, 0};
        *(bf16x8*)(base + 16 * 1024 + ((32 | r) << 4)) = z;
    }
}

// ---------------------------------------------------------------------------
// K0b: W [1024][256] f32 -> transposed split-bf16 WT_hi/WT_lo [256][1024].
// ---------------------------------------------------------------------------
__global__ __launch_bounds__(256) void k0b_wsplit(const float4* __restrict__ W,
                                                  ushort* __restrict__ WTh,
                                                  ushort* __restrict__ WTl) {
    __shared__ float lds[16][260];
    int slab = blockIdx.x;              // 64 slabs of 16 k-rows
    int tid = threadIdx.x;
    #pragma unroll
    for (int jj = 0; jj < 4; ++jj) {
        int v = jj * 256 + tid;         // 0..1023
        int row = v >> 6, f4 = v & 63;
        float4 d = W[(size_t)(slab * 16 + row) * W_F4 + f4];
        *(float4*)&lds[row][f4 * 4] = d;
    }
    __syncthreads();
    int c = tid;                        // column (n) 0..255
    #pragma unroll
    for (int kb = 0; kb < 2; ++kb) {
        bf16x8 h, l;
        #pragma unroll
        for (int j = 0; j < 8; ++j) {
            float x = lds[kb * 8 + j][c];
            union { float f; uint32_t u; } v; v.f = x;
            h[j] = (short)(v.u >> 16);
            union { uint32_t u; float f; } t; t.u = v.u & 0xFFFF0000u;
            l[j] = (short)f2bf(x - t.f);
        }
        size_t off = (size_t)c * 1024 + slab * 16 + kb * 8;
        *(bf16x8*)(WTh + off) = h;
        *(bf16x8*)(WTl + off) = l;
    }
}

// ---------------------------------------------------------------------------
// K1: z_pre = x @ W_down via split-bf16 MFMA (Ootomo 3-term: hh + hl + lh).
// (unchanged — will surface in top-5 with counters once k2 drops)
// ---------------------------------------------------------------------------
__global__ __launch_bounds__(256, 2) void k1_gemm1(const float4* __restrict__ X,
                                                   const ushort* __restrict__ WTh,
                                                   const ushort* __restrict__ WTl,
                                                   float4* __restrict__ Zp) {
    __shared__ __align__(16) char lds[65536];
    char* Ah = lds;              // 128 rows x 64 bf16 (swizzled chunks)
    char* Al = lds + 16384;
    char* Bh = lds + 32768;      // 128 cols(n) x 64 bf16
    char* Bl = lds + 49152;

    int tid  = threadIdx.x;
    int w    = tid >> 6, lane = tid & 63;
    int wm   = w >> 1, wn = w & 1;
    int c    = lane & 15, q = lane >> 4;
    int mb   = blockIdx.x >> 1, nb = blockIdx.x & 1;
    int m0   = mb * 128;
    int n0   = nb * 128;

    auto issue_loads = [&](int kt, float4* ga, bf16x8* gbh, bf16x8* gbl) {
        #pragma unroll
        for (int jj = 0; jj < 4; ++jj) {
            int v = jj * 256 + tid;           // 0..1023
            int row = v >> 3, ch = v & 7;
            const float4* p = X + (size_t)(m0 + row) * X_F4 + kt * 16 + ch * 2;
            ga[jj * 2]     = p[0];
            ga[jj * 2 + 1] = p[1];
        }
        #pragma unroll
        for (int jj = 0; jj < 4; ++jj) {
            int v = jj * 256 + tid;
            int col = v >> 3, ch = v & 7;
            size_t off = (size_t)(n0 + col) * 1024 + kt * 64 + ch * 8;
            gbh[jj] = *(const bf16x8*)(WTh + off);
            gbl[jj] = *(const bf16x8*)(WTl + off);
        }
    };
    auto write_lds = [&](const float4* ga, const bf16x8* gbh, const bf16x8* gbl) {
        #pragma unroll
        for (int jj = 0; jj < 4; ++jj) {
            int v = jj * 256 + tid;
            int row = v >> 3, ch = v & 7;
            bf16x8 h, l;
            split8(ga[jj * 2], ga[jj * 2 + 1], h, l);
            int off = row * 128 + ((ch ^ (row & 7)) << 4);
            *(bf16x8*)(Ah + off) = h;
            *(bf16x8*)(Al + off) = l;
        }
        #pragma unroll
        for (int jj = 0; jj < 4; ++jj) {
            int v = jj * 256 + tid;
            int col = v >> 3, ch = v & 7;
            int off = col * 128 + ((ch ^ (col & 7)) << 4);
            *(bf16x8*)(Bh + off) = gbh[jj];
            *(bf16x8*)(Bl + off) = gbl[jj];
        }
    };

    floatx4 acc[4][4];
    #pragma unroll
    for (int i = 0; i < 4; ++i)
        #pragma unroll
        for (int j = 0; j < 4; ++j) acc[i][j] = (floatx4){0.f, 0.f, 0.f, 0.f};

    float4 ga[8]; bf16x8 gbh[4], gbl[4];
    issue_loads(0, ga, gbh, gbl);
    write_lds(ga, gbh, gbl);

    for (int kt = 0; kt < 16; ++kt) {
        __syncthreads();
        if (kt < 15) issue_loads(kt + 1, ga, gbh, gbl);

        #pragma unroll
        for (int ks = 0; ks < 2; ++ks) {
            bf16x8 xh[4], xl[4], wh[4], wl[4];
            #pragma unroll
            for (int i = 0; i < 4; ++i) {
                int xrow = wm * 64 + i * 16 + c;
                int xoff = xrow * 128 + (((ks * 4 + q) ^ (xrow & 7)) << 4);
                xh[i] = *(const bf16x8*)(Ah + xoff);
                xl[i] = *(const bf16x8*)(Al + xoff);
                int wrow = wn * 64 + i * 16 + c;
                int woff = wrow * 128 + (((ks * 4 + q) ^ (wrow & 7)) << 4);
                wh[i] = *(const bf16x8*)(Bh + woff);
                wl[i] = *(const bf16x8*)(Bl + woff);
            }
            #pragma unroll
            for (int xi = 0; xi < 4; ++xi)
                #pragma unroll
                for (int ni = 0; ni < 4; ++ni) {
                    acc[xi][ni] = __builtin_amdgcn_mfma_f32_16x16x32_bf16(wh[ni], xh[xi], acc[xi][ni], 0, 0, 0);
                    acc[xi][ni] = __builtin_amdgcn_mfma_f32_16x16x32_bf16(wh[ni], xl[xi], acc[xi][ni], 0, 0, 0);
                    acc[xi][ni] = __builtin_amdgcn_mfma_f32_16x16x32_bf16(wl[ni], xh[xi], acc[xi][ni], 0, 0, 0);
                }
        }

        __syncthreads();
        if (kt < 15) write_lds(ga, gbh, gbl);
    }

    #pragma unroll
    for (int xi = 0; xi < 4; ++xi) {
        int tok = m0 + wm * 64 + xi * 16 + c;
        #pragma unroll
        for (int ni = 0; ni < 4; ++ni) {
            int nf4 = nb * 32 + wn * 16 + ni * 4 + q;
            float4 o;
            o.x = acc[xi][ni][0]; o.y = acc[xi][ni][1];
            o.z = acc[xi][ni][2]; o.w = acc[xi][ni][3];
            Zp[(size_t)tok * Z_F4 + nf4] = o;
        }
    }
}

// ---------------------------------------------------------------------------
// K1b: z = (z_pre + b) / (||z_pre + b|| + 1e-6) (unchanged)
// ---------------------------------------------------------------------------
__global__ __launch_bounds__(256) void k1b_norm(float4* __restrict__ Z,
                                                const float4* __restrict__ bias) {
    int wid = threadIdx.x >> 6, lane = threadIdx.x & 63;
    int t = blockIdx.x * 4 + wid;
    float4 b = bias[lane];
    float4 z = Z[(size_t)t * Z_F4 + lane];
    z.x += b.x; z.y += b.y; z.z += b.z; z.w += b.w;
    double ss = (double)z.x*z.x + (double)z.y*z.y + (double)z.z*z.z + (double)z.w*z.w;
    #pragma unroll
    for (int m = 32; m >= 1; m >>= 1) ss += __shfl_xor(ss, m, 64);
    float inv = 1.0f / ((float)sqrt(ss) + 1e-6f);
    z.x *= inv; z.y *= inv; z.z *= inv; z.w *= inv;
    Z[(size_t)t * Z_F4 + lane] = z;
}

// ---------------------------------------------------------------------------
// K2 v4b: v4 + sched_barrier(0) fence after each prefetch-load loop.
// The fence (rule #18/T19) stops the LLVM scheduler from sinking the A1/A0
// prefetch loads into the consuming tile (v3/v4 collapsed the register
// double-buffer to VGPR=116/132, serializing load->wait->MFMA per tile).
// With the fence, loads issue BEFORE compute of the current tile and their
// s_waitcnt lands at first use one tile later — true software pipeline.
// Expected VGPR ~236 (Bt 68 + A0 68 + A1 68 + Cc 16 + keys/addr), fits
// launch_bounds(256,2) budget 256 with no spill.
// ---------------------------------------------------------------------------
__global__ __launch_bounds__(256, 2) void k2_mfma(const float* __restrict__ Z,
                                                  const ushort* __restrict__ Cbb2,
                                                  int4* __restrict__ cands) {
    __shared__ uint32_t Mk[64][4][4];   // [token][wc*2+hi][rank]

    int tid  = threadIdx.x;
    int w    = tid >> 6;
    int wm   = w >> 1;           // token group
    int wc   = w & 1;            // code half
    int lane = tid & 63;
    int r    = lane & 31;
    int hi   = lane >> 5;
    int t0   = blockIdx.x * 64;

    // ---- resident token fragments (B-operand): col=r, k = f*16 + hi*8 + j
    bf16x8 Bt[17];
    #pragma unroll
    for (int f = 0; f < 16; ++f) {
        const float* zp = Z + (size_t)(t0 + wm * 32 + r) * CD + f * 16 + hi * 8;
        float4 f0 = *(const float4*)zp;
        float4 f1 = *(const float4*)(zp + 4);
        bf16x8 b;
        b[0] = (short)f2bf(f0.x); b[1] = (short)f2bf(f0.y);
        b[2] = (short)f2bf(f0.z); b[3] = (short)f2bf(f0.w);
        b[4] = (short)f2bf(f1.x); b[5] = (short)f2bf(f1.y);
        b[6] = (short)f2bf(f1.z); b[7] = (short)f2bf(f1.w);
        Bt[f] = b;
    }
    {
        bf16x8 b = (bf16x8){0, 0, 0, 0, 0, 0, 0, 0};
        if (hi == 0) { b[0] = (short)0x3F80; b[1] = (short)0x3F80; }  // 1.0,1.0
        Bt[16] = b;
    }

    // ---- streaming A addresses: lane IS the fragment slot (coalesced)
    const char* half = (const char*)Cbb2 + (size_t)(wc * 64) * TILE_B;
    int l0 = (wc == 0 && r == 0) ? (lane + 1) : lane;  // clamp code0 slot @tile0
    const char* ap0 = half + l0 * 16;
    const char* apL = half + lane * 16;

    float K1f = 0.0f, K2f = 0.0f, K3f = 0.0f, K4f = 0.0f;

    bf16x8 A0[17], A1[17];
    #pragma unroll
    for (int f = 0; f < 17; ++f) A0[f] = *(const bf16x8*)(ap0 + f * 1024);
    __builtin_amdgcn_sched_barrier(0);

    const char* ap = apL + TILE_B;                     // next tile

    auto compute = [&](const bf16x8 (&Ax)[17], int ct) {
        floatx16 Cc;
        #pragma unroll
        for (int i = 0; i < 16; ++i) Cc[i] = 0.0f;
        #pragma unroll
        for (int f = 0; f < 17; ++f)
            Cc = __builtin_amdgcn_mfma_f32_32x32x16_bf16(Ax[f], Bt[f], Cc, 0, 0, 0);
        #pragma unroll
        for (int reg = 0; reg < 16; ++reg) {
            union { float f; uint32_t u; } uv; uv.f = Cc[reg];
            uint32_t ku = (uv.u & 0xFFFFF800u) | ((uint32_t)ct << 4) | (uint32_t)reg;
            union { uint32_t u; float f; } kv; kv.u = ku;
            float k = kv.f;
            K4f = __builtin_amdgcn_fmed3f(K3f, K4f, k);
            K3f = __builtin_amdgcn_fmed3f(K2f, K3f, k);
            K2f = __builtin_amdgcn_fmed3f(K1f, K2f, k);
            K1f = fmaxf(K1f, k);
        }
    };

    for (int ctl = 0; ctl < 64; ctl += 2) {
        #pragma unroll
        for (int f = 0; f < 17; ++f) A1[f] = *(const bf16x8*)(ap + f * 1024);
        __builtin_amdgcn_sched_barrier(0);   // pin prefetch issue before compute
        ap += TILE_B;
        compute(A0, wc * 64 + ctl);
        const char* apn = (ctl + 2 < 64) ? ap : apL;   // clamp last prefetch
        #pragma unroll
        for (int f = 0; f < 17; ++f) A0[f] = *(const bf16x8*)(apn + f * 1024);
        __builtin_amdgcn_sched_barrier(0);   // pin prefetch issue before compute
        ap += TILE_B;
        compute(A1, wc * 64 + ctl + 1);
        if ((ctl & 15) == 14) __builtin_amdgcn_s_barrier();  // wave alignment
    }

    // ---- merge: per token 4 sources (wc x hi) x top-4 -> global top-4
    {
        int lt = wm * 32 + r, src = wc * 2 + hi;
        union { float f; uint32_t u; } a, b, c, d;
        a.f = K1f; b.f = K2f; c.f = K3f; d.f = K4f;
        Mk[lt][src][0] = a.u; Mk[lt][src][1] = b.u;
        Mk[lt][src][2] = c.u; Mk[lt][src][3] = d.u;
    }
    __syncthreads();

    if (tid < 64) {
        uint32_t bk0 = 0, bk1 = 0, bk2 = 0, bk3 = 0;
        uint32_t be0 = 0, be1 = 0, be2 = 0, be3 = 0;
        #pragma unroll
        for (int s = 0; s < 4; ++s) {
            #pragma unroll
            for (int j = 0; j < 4; ++j) {
                uint32_t key = Mk[tid][s][j];
                uint32_t e = (uint32_t)s;           // hi = s&1
                if (key > bk0) {
                    bk3 = bk2; be3 = be2; bk2 = bk1; be2 = be1;
                    bk1 = bk0; be1 = be0; bk0 = key; be0 = e;
                } else if (key > bk1) {
                    bk3 = bk2; be3 = be2; bk2 = bk1; be2 = be1; bk1 = key; be1 = e;
                } else if (key > bk2) {
                    bk3 = bk2; be3 = be2; bk2 = key; be2 = e;
                } else if (key > bk3) {
                    bk3 = key; be3 = e;
                }
            }
        }
        auto dec = [&](uint32_t key, uint32_t e) -> int {
            int ct = (int)((key >> 4) & 127u);
            int rg = (int)(key & 15u);
            int row = (rg & 3) + 8 * (rg >> 2) + 4 * (int)(e & 1);
            int code = ct * 32 + row;
            return code < 1 ? 1 : code;
        };
        int4 out;
        out.x = dec(bk0, be0); out.y = dec(bk1, be1);
        out.z = dec(bk2, be2); out.w = dec(bk3, be3);
        cands[t0 + tid] = out;
    }
}

// ---------------------------------------------------------------------------
// K3: f64 re-rank of 4 candidates (code 0 invalid; ties -> lowest index),
// write index (as float) + gather hard code. One wave per token.
// ---------------------------------------------------------------------------
__global__ __launch_bounds__(256) void k3_refine(const float4* __restrict__ Z,
                                                 const float4* __restrict__ Cb,
                                                 const int4* __restrict__ cands,
                                                 float* __restrict__ idxOut,
                                                 float4* __restrict__ hardOut) {
    int wid = threadIdx.x >> 6, lane = threadIdx.x & 63;
    int t = blockIdx.x * 4 + wid;
    int4 cd = cands[t];
    int cc[4] = {cd.x, cd.y, cd.z, cd.w};
    float4 z = Z[(size_t)t * Z_F4 + lane];
    double best = -1.0e300;
    int bi = NC;   // sentinel
    #pragma unroll
    for (int e = 0; e < 4; ++e) {
        int idx = cc[e];
        float4 cf = Cb[(size_t)idx * C_F4 + lane];
        double dot = (double)z.x*cf.x + (double)z.y*cf.y + (double)z.z*cf.z + (double)z.w*cf.w;
        double nrm = (double)cf.x*cf.x + (double)cf.y*cf.y + (double)cf.z*cf.z + (double)cf.w*cf.w;
        #pragma unroll
        for (int m = 32; m >= 1; m >>= 1) {
            dot += __shfl_xor(dot, m, 64);
            nrm += __shfl_xor(nrm, m, 64);
        }
        double s = dot - 0.5 * nrm;
        if (idx >= 1 && (s > best || (s == best && idx < bi))) { best = s; bi = idx; }
    }
    if (lane == 0) idxOut[t] = (float)bi;
    hardOut[(size_t)t * C_F4 + lane] = Cb[(size_t)bi * C_F4 + lane];
}

// ---------------------------------------------------------------------------
extern "C" void kernel_launch(void* const* d_in, const int* in_sizes, int n_in,
                              void* d_out, int out_size, void* d_ws, size_t ws_size,
                              hipStream_t stream) {
    const float* x  = (const float*)d_in[0];   // 32768 x 1024
    const float* cb = (const float*)d_in[1];   // 4096 x 256
    const float* w  = (const float*)d_in[2];   // 1024 x 256
    const float* bd = (const float*)d_in[3];   // 256

    float* zOut    = (float*)d_out;                    // 32768 x 256
    float* idxOut  = zOut + (size_t)NT * CD;           // 32768 (as float values)
    float* hardOut = idxOut + NT;                      // 32768 x 256

    int4*   cands = (int4*)d_ws;                             // 512 KB
    ushort* cbb2  = (ushort*)((char*)d_ws + 524288);         // 128*17408 = 2,228,224 B
    ushort* wth   = (ushort*)((char*)d_ws + 2752512);        // 512 KB bf16 W^T hi
    ushort* wtl   = (ushort*)((char*)d_ws + 3276800);        // 512 KB bf16 W^T lo

    k0_prep<<<NC / 8, 256, 0, stream>>>((const float4*)cb, cbb2);
    k0b_wsplit<<<DM / 16, 256, 0, stream>>>((const float4*)w, wth, wtl);
    k1_gemm1<<<(NT / 128) * 2, 256, 0, stream>>>((const float4*)x, wth, wtl,
                                                 (float4*)zOut);
    k1b_norm<<<NT / 4, 256, 0, stream>>>((float4*)zOut, (const float4*)bd);
    k2_mfma<<<NT / 64, 256, 0, stream>>>(zOut, cbb2, cands);
    k3_refine<<<NT / 4, 256, 0, stream>>>((const float4*)zOut, (const float4*)cb,
                                          cands, idxOut, (float4*)hardOut);
}